// Round 1
// baseline (1470.559 us; speedup 1.0000x reference)
//
#include <hip/hip_runtime.h>

// ---------------- CSR build ----------------

__global__ __launch_bounds__(256) void k_hist(const int* __restrict__ dst, int* __restrict__ cnt, int E){
  int i = blockIdx.x*256 + threadIdx.x;
  if(i < E) atomicAdd(&cnt[dst[i]], 1);
}

__global__ __launch_bounds__(256) void k_scan_part(const int* __restrict__ cnt, int* __restrict__ bsum, int N){
  __shared__ int s[256];
  int t = threadIdx.x;
  int i = blockIdx.x*256 + t;
  s[t] = (i < N) ? cnt[i] : 0;
  __syncthreads();
  for(int off=128; off>0; off>>=1){
    if(t < off) s[t] += s[t+off];
    __syncthreads();
  }
  if(t == 0) bsum[blockIdx.x] = s[0];
}

// nb (number of partial blocks) must be <= 512; N=100000 -> nb=391.
__global__ __launch_bounds__(512) void k_scan_top(int* __restrict__ bsum, int* __restrict__ rp, int nb, int N){
  __shared__ int s[512];
  int t = threadIdx.x;
  int v = (t < nb) ? bsum[t] : 0;
  s[t] = v;
  __syncthreads();
  for(int off=1; off<512; off<<=1){
    int x = 0;
    if(t >= off) x = s[t-off];
    __syncthreads();
    if(t >= off) s[t] += x;
    __syncthreads();
  }
  if(t < nb) bsum[t] = s[t] - v;   // exclusive prefix of block sums
  if(t == 511) rp[N] = s[511];     // total = E
}

__global__ __launch_bounds__(256) void k_scan_down(const int* __restrict__ cnt, const int* __restrict__ bsum,
                                                   int* __restrict__ rp, int N){
  __shared__ int s[256];
  int t = threadIdx.x;
  int i = blockIdx.x*256 + t;
  int v = (i < N) ? cnt[i] : 0;
  s[t] = v;
  __syncthreads();
  for(int off=1; off<256; off<<=1){
    int x = 0;
    if(t >= off) x = s[t-off];
    __syncthreads();
    if(t >= off) s[t] += x;
    __syncthreads();
  }
  if(i < N) rp[i] = bsum[blockIdx.x] + s[t] - v;
}

__global__ __launch_bounds__(256) void k_scatter(const int* __restrict__ src, const int* __restrict__ dst,
                                                 int* __restrict__ cur, int* __restrict__ esrc, int E){
  int i = blockIdx.x*256 + threadIdx.x;
  if(i < E){
    int p = atomicAdd(&cur[dst[i]], 1);
    esrc[p] = src[i];
  }
}

// ---------------- layer 0 input projections ----------------
// x:[N,9] -> hs = x@w_src+b_src, hd = x@w_dst+b_dst  (both [N,64])
__global__ __launch_bounds__(256) void k_proj(const float* __restrict__ x,
                                              const float* __restrict__ ws, const float* __restrict__ bs,
                                              const float* __restrict__ wd, const float* __restrict__ bd,
                                              float* __restrict__ hs, float* __restrict__ hd, int N){
  int gid = blockIdx.x*256 + threadIdx.x;
  int n = gid >> 6, c = gid & 63;
  if(n >= N) return;
  float as = bs[c], ad = bd[c];
  const float* xr = x + (size_t)n*9;
  #pragma unroll
  for(int k=0;k<9;++k){
    float xv = xr[k];                       // wave-broadcast (same addr across 64 lanes)
    as += xv * ws[k*64 + c];                // coalesced, tiny & cached
    ad += xv * wd[k*64 + c];
  }
  hs[(size_t)n*64 + c] = as;
  hd[(size_t)n*64 + c] = ad;
}

// ---------------- edge phase: softmax-aggregate, one wave per node ----------------
// y[n,c] = segsoftmax-weighted-sum of msg + xd[n,c];  msg = relu(xs[src,c]) + 1e-7
__global__ __launch_bounds__(256) void k_edge(const float* __restrict__ xs, const float* __restrict__ xd,
                                              const int* __restrict__ rp, const int* __restrict__ es,
                                              float* __restrict__ y, int N){
  int gid = blockIdx.x*256 + threadIdx.x;
  int n = gid >> 6, lane = gid & 63;
  if(n >= N) return;
  int beg = rp[n], end = rp[n+1];
  float m = -1e30f;
  for(int e=beg; e<end; ++e){
    int s = es[e];                           // wave-uniform
    float v = xs[(size_t)s*64 + lane];       // coalesced 256B row gather
    float msg = fmaxf(v, 0.f) + 1e-7f;
    m = fmaxf(m, msg);
  }
  float ss = 0.f, ts = 0.f;
  for(int e=beg; e<end; ++e){
    int s = es[e];
    float v = xs[(size_t)s*64 + lane];       // re-read: L1/L2 hot
    float msg = fmaxf(v, 0.f) + 1e-7f;
    float p = __expf(msg - m);               // p in (0,1]
    ss += p;
    ts += p * msg;
  }
  float aggr = (end > beg) ? (ts / (ss + 1e-16f)) : 0.f;
  y[(size_t)n*64 + lane] = aggr + xd[(size_t)n*64 + lane];
}

// ---------------- MLP part 1: h1 = y @ w1 + b1   [N,64]x[64,128] ----------------
// block=256: 32 nodes/block, thread = (node-quad, jq); 16 FMA per ds_read_b128
__global__ __launch_bounds__(256) void k_mlp1(const float* __restrict__ y, const float* __restrict__ w1,
                                              const float* __restrict__ b1, float* __restrict__ h1, int N){
  __shared__ float w1s[64*128];
  int t = threadIdx.x;
  for(int r=t; r<64*128; r+=256) w1s[r] = w1[r];
  __syncthreads();
  int jq = t & 31;
  int nb = blockIdx.x*32 + (t >> 5)*4;
  int n0 = nb+0 < N ? nb+0 : N-1;
  int n1 = nb+1 < N ? nb+1 : N-1;
  int n2 = nb+2 < N ? nb+2 : N-1;
  int n3 = nb+3 < N ? nb+3 : N-1;
  const float* p0 = y + (size_t)n0*64;
  const float* p1 = y + (size_t)n1*64;
  const float* p2 = y + (size_t)n2*64;
  const float* p3 = y + (size_t)n3*64;
  float4 acc0, acc1, acc2, acc3;
  acc0 = acc1 = acc2 = acc3 = *(const float4*)(b1 + jq*4);
  for(int k=0; k<64; ++k){
    float4 w = *(const float4*)(w1s + k*128 + jq*4);
    float v0 = p0[k], v1 = p1[k], v2 = p2[k], v3 = p3[k];  // wave-broadcast
    acc0.x += v0*w.x; acc0.y += v0*w.y; acc0.z += v0*w.z; acc0.w += v0*w.w;
    acc1.x += v1*w.x; acc1.y += v1*w.y; acc1.z += v1*w.z; acc1.w += v1*w.w;
    acc2.x += v2*w.x; acc2.y += v2*w.y; acc2.z += v2*w.z; acc2.w += v2*w.w;
    acc3.x += v3*w.x; acc3.y += v3*w.y; acc3.z += v3*w.z; acc3.w += v3*w.w;
  }
  if(nb+0 < N) *(float4*)(h1 + (size_t)(nb+0)*128 + jq*4) = acc0;
  if(nb+1 < N) *(float4*)(h1 + (size_t)(nb+1)*128 + jq*4) = acc1;
  if(nb+2 < N) *(float4*)(h1 + (size_t)(nb+2)*128 + jq*4) = acc2;
  if(nb+3 < N) *(float4*)(h1 + (size_t)(nb+3)*128 + jq*4) = acc3;
}

// ---------------- BN column reduction: sum & sumsq per channel ----------------
__global__ __launch_bounds__(128) void k_bnred(const float* __restrict__ h1, float* __restrict__ bn, int N){
  int j = threadIdx.x;          // 128 channels
  int chunk = (N + gridDim.x - 1) / gridDim.x;
  int a = blockIdx.x * chunk;
  int b = a + chunk; if(b > N) b = N;
  float s = 0.f, ss = 0.f;
  for(int n=a; n<b; ++n){
    float v = h1[(size_t)n*128 + j];   // 512B coalesced
    s += v; ss += v*v;
  }
  atomicAdd(&bn[j], s);
  atomicAdd(&bn[128+j], ss);
}

__global__ __launch_bounds__(128) void k_bnfold(const float* __restrict__ bn, const float* __restrict__ g,
                                                const float* __restrict__ be, float* __restrict__ sb, float invN){
  int j = threadIdx.x;
  float mu = bn[j]*invN;
  float var = bn[128+j]*invN - mu*mu;
  float sc = g[j] * rsqrtf(var + 1e-5f);
  sb[j] = sc;
  sb[128+j] = be[j] - mu*sc;
}

// ---------------- MLP part 2: hout = relu( relu(bn(h1)) @ w2 + b2 )  [N,128]x[128,64] ----------------
// block=256: 64 nodes/block; act in LDS (stride 132 -> 2-way aliasing = free), w2 from L1.
__global__ __launch_bounds__(256) void k_mlp2(const float* __restrict__ h1, const float* __restrict__ sb,
                                              const float* __restrict__ w2, const float* __restrict__ b2,
                                              float* __restrict__ hout, int N){
  __shared__ float act[64*132];
  int t = threadIdx.x;
  int n0 = blockIdx.x*64;
  for(int r=0; r<32; ++r){
    int idx = r*256 + t;
    int nl = idx >> 7, k = idx & 127;
    int n = n0 + nl;
    float v = (n < N) ? h1[(size_t)n*128 + k] : 0.f;
    v = v * sb[k] + sb[128+k];
    act[nl*132 + k] = fmaxf(v, 0.f);
  }
  __syncthreads();
  int cq = t & 15, m0 = (t >> 4)*4;
  const float4* w2v = (const float4*)w2;
  float4 acc0, acc1, acc2, acc3;
  acc0 = acc1 = acc2 = acc3 = *(const float4*)(b2 + cq*4);
  for(int k=0; k<128; ++k){
    float4 w = w2v[k*16 + cq];               // L1-resident 32KB, broadcast across node groups
    float a0 = act[(m0+0)*132 + k];
    float a1 = act[(m0+1)*132 + k];
    float a2 = act[(m0+2)*132 + k];
    float a3 = act[(m0+3)*132 + k];
    acc0.x += a0*w.x; acc0.y += a0*w.y; acc0.z += a0*w.z; acc0.w += a0*w.w;
    acc1.x += a1*w.x; acc1.y += a1*w.y; acc1.z += a1*w.z; acc1.w += a1*w.w;
    acc2.x += a2*w.x; acc2.y += a2*w.y; acc2.z += a2*w.z; acc2.w += a2*w.w;
    acc3.x += a3*w.x; acc3.y += a3*w.y; acc3.z += a3*w.z; acc3.w += a3*w.w;
  }
  acc0.x=fmaxf(acc0.x,0.f); acc0.y=fmaxf(acc0.y,0.f); acc0.z=fmaxf(acc0.z,0.f); acc0.w=fmaxf(acc0.w,0.f);
  acc1.x=fmaxf(acc1.x,0.f); acc1.y=fmaxf(acc1.y,0.f); acc1.z=fmaxf(acc1.z,0.f); acc1.w=fmaxf(acc1.w,0.f);
  acc2.x=fmaxf(acc2.x,0.f); acc2.y=fmaxf(acc2.y,0.f); acc2.z=fmaxf(acc2.z,0.f); acc2.w=fmaxf(acc2.w,0.f);
  acc3.x=fmaxf(acc3.x,0.f); acc3.y=fmaxf(acc3.y,0.f); acc3.z=fmaxf(acc3.z,0.f); acc3.w=fmaxf(acc3.w,0.f);
  if(n0+m0+0 < N) *(float4*)(hout + (size_t)(n0+m0+0)*64 + cq*4) = acc0;
  if(n0+m0+1 < N) *(float4*)(hout + (size_t)(n0+m0+1)*64 + cq*4) = acc1;
  if(n0+m0+2 < N) *(float4*)(hout + (size_t)(n0+m0+2)*64 + cq*4) = acc2;
  if(n0+m0+3 < N) *(float4*)(hout + (size_t)(n0+m0+3)*64 + cq*4) = acc3;
}

// ---------------- fused mean-pool + dense + sigmoid (batch_idx is sorted -> binary search) ----------------
__device__ __forceinline__ int lbound(const int* a, int n, int key){
  int lo = 0, hi = n;
  while(lo < hi){
    int mid = (lo + hi) >> 1;
    if(a[mid] < key) lo = mid + 1; else hi = mid;
  }
  return lo;
}

__global__ __launch_bounds__(256) void k_pool(const float* __restrict__ h, const int* __restrict__ batch,
                                              const float* __restrict__ wd, const float* __restrict__ bd,
                                              float* __restrict__ out, int N){
  int g = blockIdx.x;
  int lo = lbound(batch, N, g);
  int hi = lbound(batch, N, g+1);
  int c = threadIdx.x & 63, w = threadIdx.x >> 6;
  float acc = 0.f;
  for(int n = lo + w; n < hi; n += 4) acc += h[(size_t)n*64 + c];
  __shared__ float red[4][64];
  red[w][c] = acc;
  __syncthreads();
  if(w == 0){
    float v = red[0][c] + red[1][c] + red[2][c] + red[3][c];
    float count = (float)(hi - lo);
    v = v / fmaxf(count, 1.f) * wd[c];
    for(int off=32; off>0; off>>=1) v += __shfl_down(v, off, 64);
    if(c == 0) out[g] = 1.f / (1.f + expf(-(v + bd[0])));
  }
}

// ---------------- host ----------------

extern "C" void kernel_launch(void* const* d_in, const int* in_sizes, int n_in,
                              void* d_out, int out_size, void* d_ws, size_t ws_size,
                              hipStream_t stream){
  const float* x      = (const float*)d_in[0];
  const int*   ei     = (const int*)  d_in[1];
  const int*   batch  = (const int*)  d_in[2];
  const float* w_src  = (const float*)d_in[3];
  const float* b_src  = (const float*)d_in[4];
  const float* w_dst  = (const float*)d_in[5];
  const float* b_dst  = (const float*)d_in[6];
  const float* w_dense= (const float*)d_in[25];
  const float* b_dense= (const float*)d_in[26];
  float* out = (float*)d_out;

  const int N = in_sizes[2];
  const int E = in_sizes[1] / 2;
  const int* src = ei;
  const int* dst = ei + E;

  // workspace layout (256B aligned)
  char* ws = (char*)d_ws;
  size_t off = 0;
  auto take = [&](size_t bytes) -> void* {
    void* p = ws + off;
    off += (bytes + 255) & ~(size_t)255;
    return p;
  };
  float* hA   = (float*)take((size_t)N*64*4);
  float* hB   = (float*)take((size_t)N*64*4);
  float* hy   = (float*)take((size_t)N*64*4);
  float* h1   = (float*)take((size_t)N*128*4);
  int*   esrc = (int*)  take((size_t)E*4);
  int*   cntn = (int*)  take((size_t)N*4);
  int*   rp   = (int*)  take((size_t)(N+1)*4);
  int*   cur  = (int*)  take((size_t)N*4);
  int*   bsum = (int*)  take(1024*4);
  float* bn   = (float*)take(256*4);
  float* sb   = (float*)take(256*4);

  const int nb256 = (N + 255) / 256;
  const int gE    = (E + 255) / 256;
  const int gN64  = (N*64 + 255) / 256;

  // ---- CSR by dst ----
  hipMemsetAsync(cntn, 0, (size_t)N*4, stream);
  k_hist     <<<gE,    256, 0, stream>>>(dst, cntn, E);
  k_scan_part<<<nb256, 256, 0, stream>>>(cntn, bsum, N);
  k_scan_top <<<1,     512, 0, stream>>>(bsum, rp, nb256, N);
  k_scan_down<<<nb256, 256, 0, stream>>>(cntn, bsum, rp, N);
  hipMemcpyAsync(cur, rp, (size_t)N*4, hipMemcpyDeviceToDevice, stream);
  k_scatter  <<<gE,    256, 0, stream>>>(src, dst, cur, esrc, E);

  // ---- layer-1 input projections ----
  k_proj<<<gN64, 256, 0, stream>>>(x, w_src, b_src, w_dst, b_dst, hA, hB, N);

  // ---- 3 conv layers ----
  const float* xs_l[3]  = { hA, hA, hB };
  const float* xd_l[3]  = { hB, hA, hB };
  float*       out_l[3] = { hA, hB, hA };
  const float invN = 1.0f / (float)N;

  for(int L=0; L<3; ++L){
    const float* w1 = (const float*)d_in[7 + 6*L + 0];
    const float* b1 = (const float*)d_in[7 + 6*L + 1];
    const float* g  = (const float*)d_in[7 + 6*L + 2];
    const float* be = (const float*)d_in[7 + 6*L + 3];
    const float* w2 = (const float*)d_in[7 + 6*L + 4];
    const float* b2 = (const float*)d_in[7 + 6*L + 5];

    k_edge<<<gN64, 256, 0, stream>>>(xs_l[L], xd_l[L], rp, esrc, hy, N);
    k_mlp1<<<(N+31)/32, 256, 0, stream>>>(hy, w1, b1, h1, N);
    hipMemsetAsync(bn, 0, 256*4, stream);
    k_bnred <<<512, 128, 0, stream>>>(h1, bn, N);
    k_bnfold<<<1,   128, 0, stream>>>(bn, g, be, sb, invN);
    k_mlp2<<<(N+63)/64, 256, 0, stream>>>(h1, sb, w2, b2, out_l[L], N);
  }

  // ---- pooled dense + sigmoid ----
  k_pool<<<512, 256, 0, stream>>>(out_l[2], batch, w_dense, b_dense, out, N);
}

// Round 2
// 935.958 us; speedup vs baseline: 1.5712x; 1.5712x over previous
//
#include <hip/hip_runtime.h>

// ---------------- CSR build ----------------

__global__ __launch_bounds__(256) void k_hist(const int* __restrict__ dst, int* __restrict__ cnt, int E){
  int i = blockIdx.x*256 + threadIdx.x;
  if(i < E) atomicAdd(&cnt[dst[i]], 1);
}

__global__ __launch_bounds__(256) void k_scan_part(const int* __restrict__ cnt, int* __restrict__ bsum, int N){
  __shared__ int s[256];
  int t = threadIdx.x;
  int i = blockIdx.x*256 + t;
  s[t] = (i < N) ? cnt[i] : 0;
  __syncthreads();
  for(int off=128; off>0; off>>=1){
    if(t < off) s[t] += s[t+off];
    __syncthreads();
  }
  if(t == 0) bsum[blockIdx.x] = s[0];
}

// nb (number of partial blocks) must be <= 512; N=100000 -> nb=391.
__global__ __launch_bounds__(512) void k_scan_top(int* __restrict__ bsum, int* __restrict__ rp, int nb, int N){
  __shared__ int s[512];
  int t = threadIdx.x;
  int v = (t < nb) ? bsum[t] : 0;
  s[t] = v;
  __syncthreads();
  for(int off=1; off<512; off<<=1){
    int x = 0;
    if(t >= off) x = s[t-off];
    __syncthreads();
    if(t >= off) s[t] += x;
    __syncthreads();
  }
  if(t < nb) bsum[t] = s[t] - v;   // exclusive prefix of block sums
  if(t == 511) rp[N] = s[511];     // total = E
}

__global__ __launch_bounds__(256) void k_scan_down(const int* __restrict__ cnt, const int* __restrict__ bsum,
                                                   int* __restrict__ rp, int N){
  __shared__ int s[256];
  int t = threadIdx.x;
  int i = blockIdx.x*256 + t;
  int v = (i < N) ? cnt[i] : 0;
  s[t] = v;
  __syncthreads();
  for(int off=1; off<256; off<<=1){
    int x = 0;
    if(t >= off) x = s[t-off];
    __syncthreads();
    if(t >= off) s[t] += x;
    __syncthreads();
  }
  if(i < N) rp[i] = bsum[blockIdx.x] + s[t] - v;
}

__global__ __launch_bounds__(256) void k_scatter(const int* __restrict__ src, const int* __restrict__ dst,
                                                 int* __restrict__ cur, int* __restrict__ esrc, int E){
  int i = blockIdx.x*256 + threadIdx.x;
  if(i < E){
    int p = atomicAdd(&cur[dst[i]], 1);
    esrc[p] = src[i];
  }
}

// ---------------- layer 0 input projections ----------------
__global__ __launch_bounds__(256) void k_proj(const float* __restrict__ x,
                                              const float* __restrict__ ws, const float* __restrict__ bs,
                                              const float* __restrict__ wd, const float* __restrict__ bd,
                                              float* __restrict__ hs, float* __restrict__ hd, int N){
  int gid = blockIdx.x*256 + threadIdx.x;
  int n = gid >> 6, c = gid & 63;
  if(n >= N) return;
  float as = bs[c], ad = bd[c];
  const float* xr = x + (size_t)n*9;
  #pragma unroll
  for(int k=0;k<9;++k){
    float xv = xr[k];
    as += xv * ws[k*64 + c];
    ad += xv * wd[k*64 + c];
  }
  hs[(size_t)n*64 + c] = as;
  hd[(size_t)n*64 + c] = ad;
}

// ---------------- edge phase: single-pass online softmax, 4 streams ----------------
// y[n,c] = segsoftmax-weighted-sum of msg + xd[n,c];  msg = relu(xs[src,c]) + 1e-7
// One wave per node (lane = channel). 4 independent online-softmax streams give
// 4 gather loads in flight per iteration (latency-bound fix); states merged at end.
__global__ __launch_bounds__(256) void k_edge(const float* __restrict__ xs, const float* __restrict__ xd,
                                              const int* __restrict__ rp, const int* __restrict__ es,
                                              float* __restrict__ y, int N){
  int gid = blockIdx.x*256 + threadIdx.x;
  int n = gid >> 6, lane = gid & 63;
  if(n >= N) return;
  int beg = rp[n], end = rp[n+1];

  float m0=-1e30f, m1=-1e30f, m2=-1e30f, m3=-1e30f;
  float s0=0.f, s1=0.f, s2=0.f, s3=0.f;
  float t0=0.f, t1=0.f, t2=0.f, t3=0.f;

  int e = beg;
  for(; e + 4 <= end; e += 4){
    int i0 = es[e+0], i1 = es[e+1], i2 = es[e+2], i3 = es[e+3];
    float v0 = xs[(size_t)i0*64 + lane];
    float v1 = xs[(size_t)i1*64 + lane];
    float v2 = xs[(size_t)i2*64 + lane];
    float v3 = xs[(size_t)i3*64 + lane];
    float g0 = fmaxf(v0,0.f)+1e-7f;
    float g1 = fmaxf(v1,0.f)+1e-7f;
    float g2 = fmaxf(v2,0.f)+1e-7f;
    float g3 = fmaxf(v3,0.f)+1e-7f;
    {
      float nm = fmaxf(m0, g0), sc = __expf(m0-nm), p = __expf(g0-nm);
      s0 = s0*sc + p; t0 = t0*sc + p*g0; m0 = nm;
    }
    {
      float nm = fmaxf(m1, g1), sc = __expf(m1-nm), p = __expf(g1-nm);
      s1 = s1*sc + p; t1 = t1*sc + p*g1; m1 = nm;
    }
    {
      float nm = fmaxf(m2, g2), sc = __expf(m2-nm), p = __expf(g2-nm);
      s2 = s2*sc + p; t2 = t2*sc + p*g2; m2 = nm;
    }
    {
      float nm = fmaxf(m3, g3), sc = __expf(m3-nm), p = __expf(g3-nm);
      s3 = s3*sc + p; t3 = t3*sc + p*g3; m3 = nm;
    }
  }
  for(; e < end; ++e){
    int i0 = es[e];
    float v0 = xs[(size_t)i0*64 + lane];
    float g0 = fmaxf(v0,0.f)+1e-7f;
    float nm = fmaxf(m0, g0), sc = __expf(m0-nm), p = __expf(g0-nm);
    s0 = s0*sc + p; t0 = t0*sc + p*g0; m0 = nm;
  }
  // merge the 4 streams
  float M = fmaxf(fmaxf(m0,m1), fmaxf(m2,m3));
  float e0 = __expf(m0-M), e1 = __expf(m1-M), e2 = __expf(m2-M), e3 = __expf(m3-M);
  float SS = s0*e0 + s1*e1 + s2*e2 + s3*e3;
  float TS = t0*e0 + t1*e1 + t2*e2 + t3*e3;
  float aggr = (end > beg) ? (TS / (SS + 1e-16f)) : 0.f;
  y[(size_t)n*64 + lane] = aggr + xd[(size_t)n*64 + lane];
}

// ---------------- MLP part 1: h1 = y @ w1 + b1   [N,64]x[64,128] ----------------
// block=256: 32 nodes/block; epilogue computes per-block BN column partials
// (sum, sumsq) into `part` so the 51 MB k_bnred re-read of h1 is eliminated.
__global__ __launch_bounds__(256) void k_mlp1(const float* __restrict__ y, const float* __restrict__ w1,
                                              const float* __restrict__ b1, float* __restrict__ h1,
                                              float* __restrict__ part, int N){
  __shared__ float w1s[64*128];
  int t = threadIdx.x;
  for(int r=t; r<64*128; r+=256) w1s[r] = w1[r];
  __syncthreads();
  int jq = t & 31;
  int nb = blockIdx.x*32 + (t >> 5)*4;
  int n0 = nb+0 < N ? nb+0 : N-1;
  int n1 = nb+1 < N ? nb+1 : N-1;
  int n2 = nb+2 < N ? nb+2 : N-1;
  int n3 = nb+3 < N ? nb+3 : N-1;
  const float* p0 = y + (size_t)n0*64;
  const float* p1 = y + (size_t)n1*64;
  const float* p2 = y + (size_t)n2*64;
  const float* p3 = y + (size_t)n3*64;
  float4 acc0, acc1, acc2, acc3;
  acc0 = acc1 = acc2 = acc3 = *(const float4*)(b1 + jq*4);
  for(int k=0; k<64; ++k){
    float4 w = *(const float4*)(w1s + k*128 + jq*4);
    float v0 = p0[k], v1 = p1[k], v2 = p2[k], v3 = p3[k];
    acc0.x += v0*w.x; acc0.y += v0*w.y; acc0.z += v0*w.z; acc0.w += v0*w.w;
    acc1.x += v1*w.x; acc1.y += v1*w.y; acc1.z += v1*w.z; acc1.w += v1*w.w;
    acc2.x += v2*w.x; acc2.y += v2*w.y; acc2.z += v2*w.z; acc2.w += v2*w.w;
    acc3.x += v3*w.x; acc3.y += v3*w.y; acc3.z += v3*w.z; acc3.w += v3*w.w;
  }
  bool q0 = nb+0 < N, q1 = nb+1 < N, q2 = nb+2 < N, q3 = nb+3 < N;
  if(q0) *(float4*)(h1 + (size_t)(nb+0)*128 + jq*4) = acc0;
  if(q1) *(float4*)(h1 + (size_t)(nb+1)*128 + jq*4) = acc1;
  if(q2) *(float4*)(h1 + (size_t)(nb+2)*128 + jq*4) = acc2;
  if(q3) *(float4*)(h1 + (size_t)(nb+3)*128 + jq*4) = acc3;

  // ---- BN partials epilogue ----
  float4 ps, pq;
  ps.x=ps.y=ps.z=ps.w=0.f; pq.x=pq.y=pq.z=pq.w=0.f;
  if(q0){ ps.x+=acc0.x; ps.y+=acc0.y; ps.z+=acc0.z; ps.w+=acc0.w;
          pq.x+=acc0.x*acc0.x; pq.y+=acc0.y*acc0.y; pq.z+=acc0.z*acc0.z; pq.w+=acc0.w*acc0.w; }
  if(q1){ ps.x+=acc1.x; ps.y+=acc1.y; ps.z+=acc1.z; ps.w+=acc1.w;
          pq.x+=acc1.x*acc1.x; pq.y+=acc1.y*acc1.y; pq.z+=acc1.z*acc1.z; pq.w+=acc1.w*acc1.w; }
  if(q2){ ps.x+=acc2.x; ps.y+=acc2.y; ps.z+=acc2.z; ps.w+=acc2.w;
          pq.x+=acc2.x*acc2.x; pq.y+=acc2.y*acc2.y; pq.z+=acc2.z*acc2.z; pq.w+=acc2.w*acc2.w; }
  if(q3){ ps.x+=acc3.x; ps.y+=acc3.y; ps.z+=acc3.z; ps.w+=acc3.w;
          pq.x+=acc3.x*acc3.x; pq.y+=acc3.y*acc3.y; pq.z+=acc3.z*acc3.z; pq.w+=acc3.w*acc3.w; }
  __syncthreads();                    // done reading w1s, reuse as reduction buffer
  float* red = w1s;                   // need 8 groups * 256 = 2048 floats
  int g = t >> 5;
  *(float4*)(red + g*256 +       jq*4) = ps;
  *(float4*)(red + g*256 + 128 + jq*4) = pq;
  __syncthreads();
  float a = 0.f;
  #pragma unroll
  for(int gg=0; gg<8; ++gg) a += red[gg*256 + t];
  part[(size_t)blockIdx.x*256 + t] = a;
}

// reduce part[nblk][256] -> bn[256] (bn must be zeroed; 32x256 atomics, negligible)
__global__ __launch_bounds__(256) void k_bnred2(const float* __restrict__ part, float* __restrict__ bn, int nblk){
  int t = threadIdx.x;
  float a = 0.f;
  for(int b = blockIdx.x; b < nblk; b += gridDim.x) a += part[(size_t)b*256 + t];
  atomicAdd(&bn[t], a);
}

__global__ __launch_bounds__(128) void k_bnfold(const float* __restrict__ bn, const float* __restrict__ g,
                                                const float* __restrict__ be, float* __restrict__ sb, float invN){
  int j = threadIdx.x;
  float mu = bn[j]*invN;
  float var = bn[128+j]*invN - mu*mu;
  float sc = g[j] * rsqrtf(var + 1e-5f);
  sb[j] = sc;
  sb[128+j] = be[j] - mu*sc;
}

// ---------------- MLP part 2: hout = relu( relu(bn(h1)) @ w2 + b2 ) ----------------
__global__ __launch_bounds__(256) void k_mlp2(const float* __restrict__ h1, const float* __restrict__ sb,
                                              const float* __restrict__ w2, const float* __restrict__ b2,
                                              float* __restrict__ hout, int N){
  __shared__ float act[64*132];
  int t = threadIdx.x;
  int n0 = blockIdx.x*64;
  for(int r=0; r<32; ++r){
    int idx = r*256 + t;
    int nl = idx >> 7, k = idx & 127;
    int n = n0 + nl;
    float v = (n < N) ? h1[(size_t)n*128 + k] : 0.f;
    v = v * sb[k] + sb[128+k];
    act[nl*132 + k] = fmaxf(v, 0.f);
  }
  __syncthreads();
  int cq = t & 15, m0 = (t >> 4)*4;
  const float4* w2v = (const float4*)w2;
  float4 acc0, acc1, acc2, acc3;
  acc0 = acc1 = acc2 = acc3 = *(const float4*)(b2 + cq*4);
  for(int k=0; k<128; ++k){
    float4 w = w2v[k*16 + cq];
    float a0 = act[(m0+0)*132 + k];
    float a1 = act[(m0+1)*132 + k];
    float a2 = act[(m0+2)*132 + k];
    float a3 = act[(m0+3)*132 + k];
    acc0.x += a0*w.x; acc0.y += a0*w.y; acc0.z += a0*w.z; acc0.w += a0*w.w;
    acc1.x += a1*w.x; acc1.y += a1*w.y; acc1.z += a1*w.z; acc1.w += a1*w.w;
    acc2.x += a2*w.x; acc2.y += a2*w.y; acc2.z += a2*w.z; acc2.w += a2*w.w;
    acc3.x += a3*w.x; acc3.y += a3*w.y; acc3.z += a3*w.z; acc3.w += a3*w.w;
  }
  acc0.x=fmaxf(acc0.x,0.f); acc0.y=fmaxf(acc0.y,0.f); acc0.z=fmaxf(acc0.z,0.f); acc0.w=fmaxf(acc0.w,0.f);
  acc1.x=fmaxf(acc1.x,0.f); acc1.y=fmaxf(acc1.y,0.f); acc1.z=fmaxf(acc1.z,0.f); acc1.w=fmaxf(acc1.w,0.f);
  acc2.x=fmaxf(acc2.x,0.f); acc2.y=fmaxf(acc2.y,0.f); acc2.z=fmaxf(acc2.z,0.f); acc2.w=fmaxf(acc2.w,0.f);
  acc3.x=fmaxf(acc3.x,0.f); acc3.y=fmaxf(acc3.y,0.f); acc3.z=fmaxf(acc3.z,0.f); acc3.w=fmaxf(acc3.w,0.f);
  if(n0+m0+0 < N) *(float4*)(hout + (size_t)(n0+m0+0)*64 + cq*4) = acc0;
  if(n0+m0+1 < N) *(float4*)(hout + (size_t)(n0+m0+1)*64 + cq*4) = acc1;
  if(n0+m0+2 < N) *(float4*)(hout + (size_t)(n0+m0+2)*64 + cq*4) = acc2;
  if(n0+m0+3 < N) *(float4*)(hout + (size_t)(n0+m0+3)*64 + cq*4) = acc3;
}

// ---------------- fused mean-pool + dense + sigmoid ----------------
__device__ __forceinline__ int lbound(const int* a, int n, int key){
  int lo = 0, hi = n;
  while(lo < hi){
    int mid = (lo + hi) >> 1;
    if(a[mid] < key) lo = mid + 1; else hi = mid;
  }
  return lo;
}

__global__ __launch_bounds__(256) void k_pool(const float* __restrict__ h, const int* __restrict__ batch,
                                              const float* __restrict__ wd, const float* __restrict__ bd,
                                              float* __restrict__ out, int N){
  int g = blockIdx.x;
  int lo = lbound(batch, N, g);
  int hi = lbound(batch, N, g+1);
  int c = threadIdx.x & 63, w = threadIdx.x >> 6;
  float acc = 0.f;
  for(int n = lo + w; n < hi; n += 4) acc += h[(size_t)n*64 + c];
  __shared__ float red[4][64];
  red[w][c] = acc;
  __syncthreads();
  if(w == 0){
    float v = red[0][c] + red[1][c] + red[2][c] + red[3][c];
    float count = (float)(hi - lo);
    v = v / fmaxf(count, 1.f) * wd[c];
    for(int off=32; off>0; off>>=1) v += __shfl_down(v, off, 64);
    if(c == 0) out[g] = 1.f / (1.f + expf(-(v + bd[0])));
  }
}

// ---------------- host ----------------

extern "C" void kernel_launch(void* const* d_in, const int* in_sizes, int n_in,
                              void* d_out, int out_size, void* d_ws, size_t ws_size,
                              hipStream_t stream){
  const float* x      = (const float*)d_in[0];
  const int*   ei     = (const int*)  d_in[1];
  const int*   batch  = (const int*)  d_in[2];
  const float* w_src  = (const float*)d_in[3];
  const float* b_src  = (const float*)d_in[4];
  const float* w_dst  = (const float*)d_in[5];
  const float* b_dst  = (const float*)d_in[6];
  const float* w_dense= (const float*)d_in[25];
  const float* b_dense= (const float*)d_in[26];
  float* out = (float*)d_out;

  const int N = in_sizes[2];
  const int E = in_sizes[1] / 2;
  const int* src = ei;
  const int* dst = ei + E;

  char* ws = (char*)d_ws;
  size_t off = 0;
  auto take = [&](size_t bytes) -> void* {
    void* p = ws + off;
    off += (bytes + 255) & ~(size_t)255;
    return p;
  };
  const int nblk1 = (N + 31) / 32;            // k_mlp1 blocks
  float* hA   = (float*)take((size_t)N*64*4);
  float* hB   = (float*)take((size_t)N*64*4);
  float* hy   = (float*)take((size_t)N*64*4);
  float* h1   = (float*)take((size_t)N*128*4);
  int*   esrc = (int*)  take((size_t)E*4);
  int*   cntn = (int*)  take((size_t)N*4);
  int*   rp   = (int*)  take((size_t)(N+1)*4);
  int*   cur  = (int*)  take((size_t)N*4);
  int*   bsum = (int*)  take(1024*4);
  float* bn   = (float*)take(256*4);
  float* sb   = (float*)take(256*4);
  float* part = (float*)take((size_t)nblk1*256*4);

  const int nb256 = (N + 255) / 256;
  const int gE    = (E + 255) / 256;
  const int gN64  = (N*64 + 255) / 256;

  // ---- CSR by dst ----
  hipMemsetAsync(cntn, 0, (size_t)N*4, stream);
  k_hist     <<<gE,    256, 0, stream>>>(dst, cntn, E);
  k_scan_part<<<nb256, 256, 0, stream>>>(cntn, bsum, N);
  k_scan_top <<<1,     512, 0, stream>>>(bsum, rp, nb256, N);
  k_scan_down<<<nb256, 256, 0, stream>>>(cntn, bsum, rp, N);
  hipMemcpyAsync(cur, rp, (size_t)N*4, hipMemcpyDeviceToDevice, stream);
  k_scatter  <<<gE,    256, 0, stream>>>(src, dst, cur, esrc, E);

  // ---- layer-1 input projections ----
  k_proj<<<gN64, 256, 0, stream>>>(x, w_src, b_src, w_dst, b_dst, hA, hB, N);

  // ---- 3 conv layers ----
  const float* xs_l[3]  = { hA, hA, hB };
  const float* xd_l[3]  = { hB, hA, hB };
  float*       out_l[3] = { hA, hB, hA };
  const float invN = 1.0f / (float)N;

  for(int L=0; L<3; ++L){
    const float* w1 = (const float*)d_in[7 + 6*L + 0];
    const float* b1 = (const float*)d_in[7 + 6*L + 1];
    const float* g  = (const float*)d_in[7 + 6*L + 2];
    const float* be = (const float*)d_in[7 + 6*L + 3];
    const float* w2 = (const float*)d_in[7 + 6*L + 4];
    const float* b2 = (const float*)d_in[7 + 6*L + 5];

    k_edge<<<gN64, 256, 0, stream>>>(xs_l[L], xd_l[L], rp, esrc, hy, N);
    k_mlp1<<<nblk1, 256, 0, stream>>>(hy, w1, b1, h1, part, N);
    hipMemsetAsync(bn, 0, 256*4, stream);
    k_bnred2<<<32, 256, 0, stream>>>(part, bn, nblk1);
    k_bnfold<<<1,  128, 0, stream>>>(bn, g, be, sb, invN);
    k_mlp2<<<(N+63)/64, 256, 0, stream>>>(h1, sb, w2, b2, out_l[L], N);
  }

  // ---- pooled dense + sigmoid ----
  k_pool<<<512, 256, 0, stream>>>(out_l[2], batch, w_dense, b_dense, out, N);
}

// Round 4
// 881.128 us; speedup vs baseline: 1.6690x; 1.0622x over previous
//
#include <hip/hip_runtime.h>

typedef unsigned short ushort_t;

__device__ __forceinline__ unsigned short f2bf(float f){
  unsigned u = __float_as_uint(f);
  u = (u + 0x7FFFu + ((u >> 16) & 1u)) >> 16;     // round-to-nearest-even
  return (unsigned short)u;
}
__device__ __forceinline__ float bf2f(unsigned short h){
  return __uint_as_float(((unsigned)h) << 16);
}

__device__ __forceinline__ void nt_load8(const int* __restrict__ p, int* out){
  #pragma unroll
  for(int k=0;k<8;++k) out[k] = __builtin_nontemporal_load(p + k);
}

// ---------------- CSR build ----------------

__global__ __launch_bounds__(256) void k_hist(const int* __restrict__ dst, int* __restrict__ cnt, int E){
  int base = (blockIdx.x*256 + threadIdx.x)*4;
  if(base + 4 <= E){
    int d0 = __builtin_nontemporal_load(dst + base + 0);
    int d1 = __builtin_nontemporal_load(dst + base + 1);
    int d2 = __builtin_nontemporal_load(dst + base + 2);
    int d3 = __builtin_nontemporal_load(dst + base + 3);
    atomicAdd(&cnt[d0], 1); atomicAdd(&cnt[d1], 1);
    atomicAdd(&cnt[d2], 1); atomicAdd(&cnt[d3], 1);
  } else {
    for(int i=base; i<E; ++i) atomicAdd(&cnt[dst[i]], 1);
  }
}

__global__ __launch_bounds__(256) void k_scan_part(const int* __restrict__ cnt, int* __restrict__ bsum, int N){
  __shared__ int s[256];
  int t = threadIdx.x;
  int i = blockIdx.x*256 + t;
  s[t] = (i < N) ? cnt[i] : 0;
  __syncthreads();
  for(int off=128; off>0; off>>=1){
    if(t < off) s[t] += s[t+off];
    __syncthreads();
  }
  if(t == 0) bsum[blockIdx.x] = s[0];
}

__global__ __launch_bounds__(512) void k_scan_top(int* __restrict__ bsum, int* __restrict__ rp, int nb, int N){
  __shared__ int s[512];
  int t = threadIdx.x;
  int v = (t < nb) ? bsum[t] : 0;
  s[t] = v;
  __syncthreads();
  for(int off=1; off<512; off<<=1){
    int x = 0;
    if(t >= off) x = s[t-off];
    __syncthreads();
    if(t >= off) s[t] += x;
    __syncthreads();
  }
  if(t < nb) bsum[t] = s[t] - v;
  if(t == 511) rp[N] = s[511];
}

__global__ __launch_bounds__(256) void k_scan_down(const int* __restrict__ cnt, const int* __restrict__ bsum,
                                                   int* __restrict__ rp, int N){
  __shared__ int s[256];
  int t = threadIdx.x;
  int i = blockIdx.x*256 + t;
  int v = (i < N) ? cnt[i] : 0;
  s[t] = v;
  __syncthreads();
  for(int off=1; off<256; off<<=1){
    int x = 0;
    if(t >= off) x = s[t-off];
    __syncthreads();
    if(t >= off) s[t] += x;
    __syncthreads();
  }
  if(i < N) rp[i] = bsum[blockIdx.x] + s[t] - v;
}

// XCD-affine scatter: 4 dst-buckets; block class = blockIdx&3 so bucket c is
// written only from XCDs {c, c+4} (blockIdx%8 round-robin heuristic; result is
// correct regardless of mapping — affinity only improves L2 write merging).
// Each class streams the full edge list (NT loads, no L2 pollution) and acts
// on its bucket's edges. Per-class esrc slice ~1.6 MB -> merges in L2.
__global__ __launch_bounds__(256) void k_scatter(const int* __restrict__ src, const int* __restrict__ dst,
                                                 int* __restrict__ cur, int* __restrict__ esrc,
                                                 int E, unsigned magic){
  const int cls = blockIdx.x & 3;
  const int chunk = blockIdx.x >> 2;
  int base = chunk*2048 + threadIdx.x*8;
  if(base >= E) return;
  if(base + 8 <= E){
    int dd[8], ss[8];
    nt_load8(dst + base, dd);
    nt_load8(src + base, ss);
    #pragma unroll
    for(int k=0;k<8;++k){
      int d = dd[k];
      int b = (int)(((unsigned long long)(unsigned)d * magic) >> 32);
      b = b > 3 ? 3 : b;
      if(b == cls){
        int p = atomicAdd(&cur[d], 1);
        esrc[p] = ss[k];
      }
    }
  } else {
    for(int i=base; i<E; ++i){
      int d = dst[i];
      int b = (int)(((unsigned long long)(unsigned)d * magic) >> 32);
      b = b > 3 ? 3 : b;
      if(b == cls){
        int p = atomicAdd(&cur[d], 1);
        esrc[p] = src[i];
      }
    }
  }
}

// ---------------- layer 0 input projections ----------------
__global__ __launch_bounds__(256) void k_proj(const float* __restrict__ x,
                                              const float* __restrict__ ws, const float* __restrict__ bs,
                                              const float* __restrict__ wd, const float* __restrict__ bd,
                                              float* __restrict__ hs, float* __restrict__ hd,
                                              ushort_t* __restrict__ h16, int N){
  int gid = blockIdx.x*256 + threadIdx.x;
  int n = gid >> 6, c = gid & 63;
  if(n >= N) return;
  float as = bs[c], ad = bd[c];
  const float* xr = x + (size_t)n*9;
  #pragma unroll
  for(int k=0;k<9;++k){
    float xv = xr[k];
    as += xv * ws[k*64 + c];
    ad += xv * wd[k*64 + c];
  }
  hs[(size_t)n*64 + c] = as;
  hd[(size_t)n*64 + c] = ad;
  h16[(size_t)n*64 + c] = f2bf(as);
}

// ---------------- edge phase: single-pass online softmax, bf16 gather ----------------
__global__ __launch_bounds__(256) void k_edge(const ushort_t* __restrict__ xs16, const float* __restrict__ xd,
                                              const int* __restrict__ rp, const int* __restrict__ es,
                                              float* __restrict__ y, int N){
  int gid = blockIdx.x*256 + threadIdx.x;
  int n = gid >> 6, lane = gid & 63;
  if(n >= N) return;
  int beg = rp[n], end = rp[n+1];

  float m0=-1e30f, m1=-1e30f, m2=-1e30f, m3=-1e30f;
  float s0=0.f, s1=0.f, s2=0.f, s3=0.f;
  float t0=0.f, t1=0.f, t2=0.f, t3=0.f;

  int e = beg;
  for(; e + 4 <= end; e += 4){
    int i0 = es[e+0], i1 = es[e+1], i2 = es[e+2], i3 = es[e+3];
    float v0 = bf2f(xs16[(size_t)i0*64 + lane]);
    float v1 = bf2f(xs16[(size_t)i1*64 + lane]);
    float v2 = bf2f(xs16[(size_t)i2*64 + lane]);
    float v3 = bf2f(xs16[(size_t)i3*64 + lane]);
    float g0 = fmaxf(v0,0.f)+1e-7f;
    float g1 = fmaxf(v1,0.f)+1e-7f;
    float g2 = fmaxf(v2,0.f)+1e-7f;
    float g3 = fmaxf(v3,0.f)+1e-7f;
    {
      float nm = fmaxf(m0, g0), sc = __expf(m0-nm), p = __expf(g0-nm);
      s0 = s0*sc + p; t0 = t0*sc + p*g0; m0 = nm;
    }
    {
      float nm = fmaxf(m1, g1), sc = __expf(m1-nm), p = __expf(g1-nm);
      s1 = s1*sc + p; t1 = t1*sc + p*g1; m1 = nm;
    }
    {
      float nm = fmaxf(m2, g2), sc = __expf(m2-nm), p = __expf(g2-nm);
      s2 = s2*sc + p; t2 = t2*sc + p*g2; m2 = nm;
    }
    {
      float nm = fmaxf(m3, g3), sc = __expf(m3-nm), p = __expf(g3-nm);
      s3 = s3*sc + p; t3 = t3*sc + p*g3; m3 = nm;
    }
  }
  for(; e < end; ++e){
    int i0 = es[e];
    float v0 = bf2f(xs16[(size_t)i0*64 + lane]);
    float g0 = fmaxf(v0,0.f)+1e-7f;
    float nm = fmaxf(m0, g0), sc = __expf(m0-nm), p = __expf(g0-nm);
    s0 = s0*sc + p; t0 = t0*sc + p*g0; m0 = nm;
  }
  float M = fmaxf(fmaxf(m0,m1), fmaxf(m2,m3));
  float e0 = __expf(m0-M), e1 = __expf(m1-M), e2 = __expf(m2-M), e3 = __expf(m3-M);
  float SS = s0*e0 + s1*e1 + s2*e2 + s3*e3;
  float TS = t0*e0 + t1*e1 + t2*e2 + t3*e3;
  float aggr = (end > beg) ? (TS / (SS + 1e-16f)) : 0.f;
  y[(size_t)n*64 + lane] = aggr + xd[(size_t)n*64 + lane];
}

// ---------------- MLP part 1 (+BN partials epilogue) ----------------
__global__ __launch_bounds__(256) void k_mlp1(const float* __restrict__ y, const float* __restrict__ w1,
                                              const float* __restrict__ b1, float* __restrict__ h1,
                                              float* __restrict__ part, int N){
  __shared__ float w1s[64*128];
  int t = threadIdx.x;
  for(int r=t; r<64*128; r+=256) w1s[r] = w1[r];
  __syncthreads();
  int jq = t & 31;
  int nb = blockIdx.x*32 + (t >> 5)*4;
  int n0 = nb+0 < N ? nb+0 : N-1;
  int n1 = nb+1 < N ? nb+1 : N-1;
  int n2 = nb+2 < N ? nb+2 : N-1;
  int n3 = nb+3 < N ? nb+3 : N-1;
  const float* p0 = y + (size_t)n0*64;
  const float* p1 = y + (size_t)n1*64;
  const float* p2 = y + (size_t)n2*64;
  const float* p3 = y + (size_t)n3*64;
  float4 acc0, acc1, acc2, acc3;
  acc0 = acc1 = acc2 = acc3 = *(const float4*)(b1 + jq*4);
  for(int k=0; k<64; ++k){
    float4 w = *(const float4*)(w1s + k*128 + jq*4);
    float v0 = p0[k], v1 = p1[k], v2 = p2[k], v3 = p3[k];
    acc0.x += v0*w.x; acc0.y += v0*w.y; acc0.z += v0*w.z; acc0.w += v0*w.w;
    acc1.x += v1*w.x; acc1.y += v1*w.y; acc1.z += v1*w.z; acc1.w += v1*w.w;
    acc2.x += v2*w.x; acc2.y += v2*w.y; acc2.z += v2*w.z; acc2.w += v2*w.w;
    acc3.x += v3*w.x; acc3.y += v3*w.y; acc3.z += v3*w.z; acc3.w += v3*w.w;
  }
  bool q0 = nb+0 < N, q1 = nb+1 < N, q2 = nb+2 < N, q3 = nb+3 < N;
  if(q0) *(float4*)(h1 + (size_t)(nb+0)*128 + jq*4) = acc0;
  if(q1) *(float4*)(h1 + (size_t)(nb+1)*128 + jq*4) = acc1;
  if(q2) *(float4*)(h1 + (size_t)(nb+2)*128 + jq*4) = acc2;
  if(q3) *(float4*)(h1 + (size_t)(nb+3)*128 + jq*4) = acc3;

  float4 ps, pq;
  ps.x=ps.y=ps.z=ps.w=0.f; pq.x=pq.y=pq.z=pq.w=0.f;
  if(q0){ ps.x+=acc0.x; ps.y+=acc0.y; ps.z+=acc0.z; ps.w+=acc0.w;
          pq.x+=acc0.x*acc0.x; pq.y+=acc0.y*acc0.y; pq.z+=acc0.z*acc0.z; pq.w+=acc0.w*acc0.w; }
  if(q1){ ps.x+=acc1.x; ps.y+=acc1.y; ps.z+=acc1.z; ps.w+=acc1.w;
          pq.x+=acc1.x*acc1.x; pq.y+=acc1.y*acc1.y; pq.z+=acc1.z*acc1.z; pq.w+=acc1.w*acc1.w; }
  if(q2){ ps.x+=acc2.x; ps.y+=acc2.y; ps.z+=acc2.z; ps.w+=acc2.w;
          pq.x+=acc2.x*acc2.x; pq.y+=acc2.y*acc2.y; pq.z+=acc2.z*acc2.z; pq.w+=acc2.w*acc2.w; }
  if(q3){ ps.x+=acc3.x; ps.y+=acc3.y; ps.z+=acc3.z; ps.w+=acc3.w;
          pq.x+=acc3.x*acc3.x; pq.y+=acc3.y*acc3.y; pq.z+=acc3.z*acc3.z; pq.w+=acc3.w*acc3.w; }
  __syncthreads();
  float* red = w1s;
  int g = t >> 5;
  *(float4*)(red + g*256 +       jq*4) = ps;
  *(float4*)(red + g*256 + 128 + jq*4) = pq;
  __syncthreads();
  float a = 0.f;
  #pragma unroll
  for(int gg=0; gg<8; ++gg) a += red[gg*256 + t];
  part[(size_t)blockIdx.x*256 + t] = a;
}

__global__ __launch_bounds__(256) void k_bnred2(const float* __restrict__ part, float* __restrict__ bn, int nblk){
  int t = threadIdx.x;
  float a = 0.f;
  for(int b = blockIdx.x; b < nblk; b += gridDim.x) a += part[(size_t)b*256 + t];
  atomicAdd(&bn[t], a);
}

__global__ __launch_bounds__(128) void k_bnfold(const float* __restrict__ bn, const float* __restrict__ g,
                                                const float* __restrict__ be, float* __restrict__ sb, float invN){
  int j = threadIdx.x;
  float mu = bn[j]*invN;
  float var = bn[128+j]*invN - mu*mu;
  float sc = g[j] * rsqrtf(var + 1e-5f);
  sb[j] = sc;
  sb[128+j] = be[j] - mu*sc;
}

// ---------------- MLP part 2 (+bf16 shadow output for next gather) ----------------
__global__ __launch_bounds__(256) void k_mlp2(const float* __restrict__ h1, const float* __restrict__ sb,
                                              const float* __restrict__ w2, const float* __restrict__ b2,
                                              float* __restrict__ hout, ushort_t* __restrict__ h16, int N){
  __shared__ float act[64*132];
  int t = threadIdx.x;
  int n0 = blockIdx.x*64;
  for(int r=0; r<32; ++r){
    int idx = r*256 + t;
    int nl = idx >> 7, k = idx & 127;
    int n = n0 + nl;
    float v = (n < N) ? h1[(size_t)n*128 + k] : 0.f;
    v = v * sb[k] + sb[128+k];
    act[nl*132 + k] = fmaxf(v, 0.f);
  }
  __syncthreads();
  int cq = t & 15, m0 = (t >> 4)*4;
  const float4* w2v = (const float4*)w2;
  float4 acc0, acc1, acc2, acc3;
  acc0 = acc1 = acc2 = acc3 = *(const float4*)(b2 + cq*4);
  for(int k=0; k<128; ++k){
    float4 w = w2v[k*16 + cq];
    float a0 = act[(m0+0)*132 + k];
    float a1 = act[(m0+1)*132 + k];
    float a2 = act[(m0+2)*132 + k];
    float a3 = act[(m0+3)*132 + k];
    acc0.x += a0*w.x; acc0.y += a0*w.y; acc0.z += a0*w.z; acc0.w += a0*w.w;
    acc1.x += a1*w.x; acc1.y += a1*w.y; acc1.z += a1*w.z; acc1.w += a1*w.w;
    acc2.x += a2*w.x; acc2.y += a2*w.y; acc2.z += a2*w.z; acc2.w += a2*w.w;
    acc3.x += a3*w.x; acc3.y += a3*w.y; acc3.z += a3*w.z; acc3.w += a3*w.w;
  }
  acc0.x=fmaxf(acc0.x,0.f); acc0.y=fmaxf(acc0.y,0.f); acc0.z=fmaxf(acc0.z,0.f); acc0.w=fmaxf(acc0.w,0.f);
  acc1.x=fmaxf(acc1.x,0.f); acc1.y=fmaxf(acc1.y,0.f); acc1.z=fmaxf(acc1.z,0.f); acc1.w=fmaxf(acc1.w,0.f);
  acc2.x=fmaxf(acc2.x,0.f); acc2.y=fmaxf(acc2.y,0.f); acc2.z=fmaxf(acc2.z,0.f); acc2.w=fmaxf(acc2.w,0.f);
  acc3.x=fmaxf(acc3.x,0.f); acc3.y=fmaxf(acc3.y,0.f); acc3.z=fmaxf(acc3.z,0.f); acc3.w=fmaxf(acc3.w,0.f);
  if(n0+m0+0 < N){
    *(float4*)(hout + (size_t)(n0+m0+0)*64 + cq*4) = acc0;
    ushort4 b; b.x=f2bf(acc0.x); b.y=f2bf(acc0.y); b.z=f2bf(acc0.z); b.w=f2bf(acc0.w);
    *(ushort4*)(h16 + (size_t)(n0+m0+0)*64 + cq*4) = b;
  }
  if(n0+m0+1 < N){
    *(float4*)(hout + (size_t)(n0+m0+1)*64 + cq*4) = acc1;
    ushort4 b; b.x=f2bf(acc1.x); b.y=f2bf(acc1.y); b.z=f2bf(acc1.z); b.w=f2bf(acc1.w);
    *(ushort4*)(h16 + (size_t)(n0+m0+1)*64 + cq*4) = b;
  }
  if(n0+m0+2 < N){
    *(float4*)(hout + (size_t)(n0+m0+2)*64 + cq*4) = acc2;
    ushort4 b; b.x=f2bf(acc2.x); b.y=f2bf(acc2.y); b.z=f2bf(acc2.z); b.w=f2bf(acc2.w);
    *(ushort4*)(h16 + (size_t)(n0+m0+2)*64 + cq*4) = b;
  }
  if(n0+m0+3 < N){
    *(float4*)(hout + (size_t)(n0+m0+3)*64 + cq*4) = acc3;
    ushort4 b; b.x=f2bf(acc3.x); b.y=f2bf(acc3.y); b.z=f2bf(acc3.z); b.w=f2bf(acc3.w);
    *(ushort4*)(h16 + (size_t)(n0+m0+3)*64 + cq*4) = b;
  }
}

// ---------------- fused mean-pool + dense + sigmoid ----------------
__device__ __forceinline__ int lbound(const int* a, int n, int key){
  int lo = 0, hi = n;
  while(lo < hi){
    int mid = (lo + hi) >> 1;
    if(a[mid] < key) lo = mid + 1; else hi = mid;
  }
  return lo;
}

__global__ __launch_bounds__(256) void k_pool(const float* __restrict__ h, const int* __restrict__ batch,
                                              const float* __restrict__ wd, const float* __restrict__ bd,
                                              float* __restrict__ out, int N){
  int g = blockIdx.x;
  int lo = lbound(batch, N, g);
  int hi = lbound(batch, N, g+1);
  int c = threadIdx.x & 63, w = threadIdx.x >> 6;
  float acc = 0.f;
  for(int n = lo + w; n < hi; n += 4) acc += h[(size_t)n*64 + c];
  __shared__ float red[4][64];
  red[w][c] = acc;
  __syncthreads();
  if(w == 0){
    float v = red[0][c] + red[1][c] + red[2][c] + red[3][c];
    float count = (float)(hi - lo);
    v = v / fmaxf(count, 1.f) * wd[c];
    for(int off=32; off>0; off>>=1) v += __shfl_down(v, off, 64);
    if(c == 0) out[g] = 1.f / (1.f + expf(-(v + bd[0])));
  }
}

// ---------------- host ----------------

extern "C" void kernel_launch(void* const* d_in, const int* in_sizes, int n_in,
                              void* d_out, int out_size, void* d_ws, size_t ws_size,
                              hipStream_t stream){
  const float* x      = (const float*)d_in[0];
  const int*   ei     = (const int*)  d_in[1];
  const int*   batch  = (const int*)  d_in[2];
  const float* w_src  = (const float*)d_in[3];
  const float* b_src  = (const float*)d_in[4];
  const float* w_dst  = (const float*)d_in[5];
  const float* b_dst  = (const float*)d_in[6];
  const float* w_dense= (const float*)d_in[25];
  const float* b_dense= (const float*)d_in[26];
  float* out = (float*)d_out;

  const int N = in_sizes[2];
  const int E = in_sizes[1] / 2;
  const int* src = ei;
  const int* dst = ei + E;

  char* ws = (char*)d_ws;
  size_t off = 0;
  auto take = [&](size_t bytes) -> void* {
    void* p = ws + off;
    off += (bytes + 255) & ~(size_t)255;
    return p;
  };
  const int nblk1 = (N + 31) / 32;
  float*    hA   = (float*)   take((size_t)N*64*4);
  float*    hB   = (float*)   take((size_t)N*64*4);
  float*    hy   = (float*)   take((size_t)N*64*4);
  float*    h1   = (float*)   take((size_t)N*128*4);
  ushort_t* h16  = (ushort_t*)take((size_t)N*64*2);
  int*      esrc = (int*)     take((size_t)E*4);
  int*      cntn = (int*)     take((size_t)N*4);
  int*      rp   = (int*)     take((size_t)(N+1)*4);
  int*      cur  = (int*)     take((size_t)N*4);
  int*      bsum = (int*)     take(1024*4);
  float*    bn   = (float*)   take(256*4);
  float*    sb   = (float*)   take(256*4);
  float*    part = (float*)   take((size_t)nblk1*256*4);

  const int nb256 = (N + 255) / 256;
  const int gN64  = (N*64 + 255) / 256;

  // bucket width = ceil(N/4); magic = ceil(2^32 / w) for d/w via mul-hi
  const unsigned w4 = (unsigned)((N + 3) / 4);
  const unsigned magic = (unsigned)(((1ull << 32) + w4 - 1) / w4);

  // ---- CSR by dst ----
  (void)hipMemsetAsync(cntn, 0, (size_t)N*4, stream);
  k_hist     <<<(E/4 + 255)/256, 256, 0, stream>>>(dst, cntn, E);
  k_scan_part<<<nb256, 256, 0, stream>>>(cntn, bsum, N);
  k_scan_top <<<1,     512, 0, stream>>>(bsum, rp, nb256, N);
  k_scan_down<<<nb256, 256, 0, stream>>>(cntn, bsum, rp, N);
  (void)hipMemcpyAsync(cur, rp, (size_t)N*4, hipMemcpyDeviceToDevice, stream);
  {
    int nchunks = (E + 2047) / 2048;
    k_scatter<<<nchunks*4, 256, 0, stream>>>(src, dst, cur, esrc, E, magic);
  }

  // ---- layer-1 input projections ----
  k_proj<<<gN64, 256, 0, stream>>>(x, w_src, b_src, w_dst, b_dst, hA, hB, h16, N);

  // ---- 3 conv layers ----
  const float* xd_l[3]  = { hB, hA, hB };
  float*       out_l[3] = { hA, hB, hA };
  const float invN = 1.0f / (float)N;

  for(int L=0; L<3; ++L){
    const float* w1 = (const float*)d_in[7 + 6*L + 0];
    const float* b1 = (const float*)d_in[7 + 6*L + 1];
    const float* g  = (const float*)d_in[7 + 6*L + 2];
    const float* be = (const float*)d_in[7 + 6*L + 3];
    const float* w2 = (const float*)d_in[7 + 6*L + 4];
    const float* b2 = (const float*)d_in[7 + 6*L + 5];

    k_edge<<<gN64, 256, 0, stream>>>(h16, xd_l[L], rp, esrc, hy, N);
    k_mlp1<<<nblk1, 256, 0, stream>>>(hy, w1, b1, h1, part, N);
    (void)hipMemsetAsync(bn, 0, 256*4, stream);
    k_bnred2<<<32, 256, 0, stream>>>(part, bn, nblk1);
    k_bnfold<<<1,  128, 0, stream>>>(bn, g, be, sb, invN);
    k_mlp2<<<(N+63)/64, 256, 0, stream>>>(h1, sb, w2, b2, out_l[L], h16, N);
  }

  // ---- pooled dense + sigmoid ----
  k_pool<<<512, 256, 0, stream>>>(out_l[2], batch, w_dense, b_dense, out, N);
}

// Round 5
// 804.290 us; speedup vs baseline: 1.8284x; 1.0955x over previous
//
#include <hip/hip_runtime.h>

typedef unsigned short ushort_t;

__device__ __forceinline__ unsigned short f2bf(float f){
  unsigned u = __float_as_uint(f);
  u = (u + 0x7FFFu + ((u >> 16) & 1u)) >> 16;     // round-to-nearest-even
  return (unsigned short)u;
}
__device__ __forceinline__ float bf2f(unsigned short h){
  return __uint_as_float(((unsigned)h) << 16);
}

__device__ __forceinline__ void nt_load8(const int* __restrict__ p, int* out){
  #pragma unroll
  for(int k=0;k<8;++k) out[k] = __builtin_nontemporal_load(p + k);
}

__device__ __forceinline__ void fma4(float4& a, float s, const float4& w){
  a.x += s*w.x; a.y += s*w.y; a.z += s*w.z; a.w += s*w.w;
}

// ---------------- CSR build ----------------

__global__ __launch_bounds__(256) void k_hist(const int* __restrict__ dst, int* __restrict__ cnt, int E){
  int base = (blockIdx.x*256 + threadIdx.x)*4;
  if(base + 4 <= E){
    int d0 = __builtin_nontemporal_load(dst + base + 0);
    int d1 = __builtin_nontemporal_load(dst + base + 1);
    int d2 = __builtin_nontemporal_load(dst + base + 2);
    int d3 = __builtin_nontemporal_load(dst + base + 3);
    atomicAdd(&cnt[d0], 1); atomicAdd(&cnt[d1], 1);
    atomicAdd(&cnt[d2], 1); atomicAdd(&cnt[d3], 1);
  } else {
    for(int i=base; i<E; ++i) atomicAdd(&cnt[dst[i]], 1);
  }
}

__global__ __launch_bounds__(256) void k_scan_part(const int* __restrict__ cnt, int* __restrict__ bsum, int N){
  __shared__ int s[256];
  int t = threadIdx.x;
  int i = blockIdx.x*256 + t;
  s[t] = (i < N) ? cnt[i] : 0;
  __syncthreads();
  for(int off=128; off>0; off>>=1){
    if(t < off) s[t] += s[t+off];
    __syncthreads();
  }
  if(t == 0) bsum[blockIdx.x] = s[0];
}

__global__ __launch_bounds__(512) void k_scan_top(int* __restrict__ bsum, int* __restrict__ rp, int nb, int N){
  __shared__ int s[512];
  int t = threadIdx.x;
  int v = (t < nb) ? bsum[t] : 0;
  s[t] = v;
  __syncthreads();
  for(int off=1; off<512; off<<=1){
    int x = 0;
    if(t >= off) x = s[t-off];
    __syncthreads();
    if(t >= off) s[t] += x;
    __syncthreads();
  }
  if(t < nb) bsum[t] = s[t] - v;
  if(t == 511) rp[N] = s[511];
}

__global__ __launch_bounds__(256) void k_scan_down(const int* __restrict__ cnt, const int* __restrict__ bsum,
                                                   int* __restrict__ rp, int* __restrict__ cur, int N){
  __shared__ int s[256];
  int t = threadIdx.x;
  int i = blockIdx.x*256 + t;
  int v = (i < N) ? cnt[i] : 0;
  s[t] = v;
  __syncthreads();
  for(int off=1; off<256; off<<=1){
    int x = 0;
    if(t >= off) x = s[t-off];
    __syncthreads();
    if(t >= off) s[t] += x;
    __syncthreads();
  }
  if(i < N){
    int p = bsum[blockIdx.x] + s[t] - v;
    rp[i] = p;
    cur[i] = p;
  }
}

// XCD-affine scatter: 4 dst-buckets; block class = blockIdx&3.
__global__ __launch_bounds__(256) void k_scatter(const int* __restrict__ src, const int* __restrict__ dst,
                                                 int* __restrict__ cur, int* __restrict__ esrc,
                                                 int E, unsigned magic){
  const int cls = blockIdx.x & 3;
  const int chunk = blockIdx.x >> 2;
  int base = chunk*2048 + threadIdx.x*8;
  if(base >= E) return;
  if(base + 8 <= E){
    int dd[8], ss[8];
    nt_load8(dst + base, dd);
    nt_load8(src + base, ss);
    #pragma unroll
    for(int k=0;k<8;++k){
      int d = dd[k];
      int b = (int)(((unsigned long long)(unsigned)d * magic) >> 32);
      b = b > 3 ? 3 : b;
      if(b == cls){
        int p = atomicAdd(&cur[d], 1);
        esrc[p] = ss[k];
      }
    }
  } else {
    for(int i=base; i<E; ++i){
      int d = dst[i];
      int b = (int)(((unsigned long long)(unsigned)d * magic) >> 32);
      b = b > 3 ? 3 : b;
      if(b == cls){
        int p = atomicAdd(&cur[d], 1);
        esrc[p] = src[i];
      }
    }
  }
}

// ---------------- layer 0 input projections ----------------
__global__ __launch_bounds__(256) void k_proj(const float* __restrict__ x,
                                              const float* __restrict__ ws, const float* __restrict__ bs,
                                              const float* __restrict__ wd, const float* __restrict__ bd,
                                              float* __restrict__ hs, float* __restrict__ hd,
                                              ushort_t* __restrict__ h16, int N){
  int gid = blockIdx.x*256 + threadIdx.x;
  int n = gid >> 6, c = gid & 63;
  if(n >= N) return;
  float as = bs[c], ad = bd[c];
  const float* xr = x + (size_t)n*9;
  #pragma unroll
  for(int k=0;k<9;++k){
    float xv = xr[k];
    as += xv * ws[k*64 + c];
    ad += xv * wd[k*64 + c];
  }
  hs[(size_t)n*64 + c] = as;
  hd[(size_t)n*64 + c] = ad;
  h16[(size_t)n*64 + c] = f2bf(as);
}

// ---------------- edge phase: direct-exp softmax aggregation, 8 streams ----------------
// msg = relu(xs)+1e-7 in [1e-7, ~5] => exp(msg) cannot overflow; max-shift of
// the reference softmax cancels algebraically: aggr = sum(e^g*g)/(sum(e^g)+1e-16).
__global__ __launch_bounds__(256) void k_edge(const ushort_t* __restrict__ xs16, const float* __restrict__ xd,
                                              const int* __restrict__ rp, const int* __restrict__ es,
                                              float* __restrict__ y, int N){
  int gid = blockIdx.x*256 + threadIdx.x;
  int n = gid >> 6, lane = gid & 63;
  if(n >= N) return;
  int beg = rp[n], end = rp[n+1];

  float ss[8], tt[8];
  #pragma unroll
  for(int j=0;j<8;++j){ ss[j]=0.f; tt[j]=0.f; }

  int e = beg;
  for(; e + 8 <= end; e += 8){
    int idx[8];
    #pragma unroll
    for(int j=0;j<8;++j) idx[j] = es[e+j];
    float g[8];
    #pragma unroll
    for(int j=0;j<8;++j) g[j] = fmaxf(bf2f(xs16[(size_t)idx[j]*64 + lane]), 0.f) + 1e-7f;
    #pragma unroll
    for(int j=0;j<8;++j){
      float p = __expf(g[j]);
      ss[j] += p; tt[j] += p*g[j];
    }
  }
  for(; e < end; ++e){
    int i0 = es[e];
    float g = fmaxf(bf2f(xs16[(size_t)i0*64 + lane]), 0.f) + 1e-7f;
    float p = __expf(g);
    ss[0] += p; tt[0] += p*g;
  }
  float S = ((ss[0]+ss[1])+(ss[2]+ss[3])) + ((ss[4]+ss[5])+(ss[6]+ss[7]));
  float T = ((tt[0]+tt[1])+(tt[2]+tt[3])) + ((tt[4]+tt[5])+(tt[6]+tt[7]));
  float aggr = T / (S + 1e-16f);
  y[(size_t)n*64 + lane] = aggr + xd[(size_t)n*64 + lane];
}

// ---------------- MLP part 1: h1 = y @ w1 + b1  (+BN partials epilogue) ----------------
// LDS-staged y rows: no per-k scalar global loads; ds_read_b128 for both w and y.
__global__ __launch_bounds__(256) void k_mlp1(const float* __restrict__ y, const float* __restrict__ w1,
                                              const float* __restrict__ b1, float* __restrict__ h1,
                                              float* __restrict__ part, int N){
  __shared__ float w1s[64*128];   // 32 KB
  __shared__ float ys[32*64];     // 8 KB
  int t = threadIdx.x;
  {
    const float4* wp = (const float4*)w1;
    float4* sp = (float4*)w1s;
    #pragma unroll
    for(int r=0;r<8;++r) sp[r*256 + t] = wp[r*256 + t];
  }
  int nbase = blockIdx.x*32;
  {
    float4* yp = (float4*)ys;
    #pragma unroll
    for(int r=0;r<2;++r){
      int idx = r*256 + t;
      int node = nbase + (idx >> 4);       // 16 float4 per row
      float4 v = {0.f,0.f,0.f,0.f};
      if(node < N) v = ((const float4*)y)[(size_t)node*16 + (idx & 15)];
      yp[idx] = v;
    }
  }
  __syncthreads();
  int jq = t & 31;
  int r0 = (t >> 5)*4;
  float4 b = ((const float4*)b1)[jq];
  float4 a0=b, a1=b, a2=b, a3=b;
  for(int k=0; k<64; k+=4){
    float4 w0 = *(const float4*)(w1s + (k+0)*128 + jq*4);
    float4 w1r= *(const float4*)(w1s + (k+1)*128 + jq*4);
    float4 w2r= *(const float4*)(w1s + (k+2)*128 + jq*4);
    float4 w3r= *(const float4*)(w1s + (k+3)*128 + jq*4);
    float4 ya = *(const float4*)(ys + (r0+0)*64 + k);
    float4 yb = *(const float4*)(ys + (r0+1)*64 + k);
    float4 yc = *(const float4*)(ys + (r0+2)*64 + k);
    float4 yd = *(const float4*)(ys + (r0+3)*64 + k);
    fma4(a0, ya.x, w0); fma4(a0, ya.y, w1r); fma4(a0, ya.z, w2r); fma4(a0, ya.w, w3r);
    fma4(a1, yb.x, w0); fma4(a1, yb.y, w1r); fma4(a1, yb.z, w2r); fma4(a1, yb.w, w3r);
    fma4(a2, yc.x, w0); fma4(a2, yc.y, w1r); fma4(a2, yc.z, w2r); fma4(a2, yc.w, w3r);
    fma4(a3, yd.x, w0); fma4(a3, yd.y, w1r); fma4(a3, yd.z, w2r); fma4(a3, yd.w, w3r);
  }
  int nb = nbase + r0;
  bool q0 = nb+0 < N, q1 = nb+1 < N, q2 = nb+2 < N, q3 = nb+3 < N;
  if(q0) *(float4*)(h1 + (size_t)(nb+0)*128 + jq*4) = a0;
  if(q1) *(float4*)(h1 + (size_t)(nb+1)*128 + jq*4) = a1;
  if(q2) *(float4*)(h1 + (size_t)(nb+2)*128 + jq*4) = a2;
  if(q3) *(float4*)(h1 + (size_t)(nb+3)*128 + jq*4) = a3;

  // ---- BN partials ----
  float4 ps, pq;
  ps.x=ps.y=ps.z=ps.w=0.f; pq.x=pq.y=pq.z=pq.w=0.f;
  if(q0){ ps.x+=a0.x; ps.y+=a0.y; ps.z+=a0.z; ps.w+=a0.w;
          pq.x+=a0.x*a0.x; pq.y+=a0.y*a0.y; pq.z+=a0.z*a0.z; pq.w+=a0.w*a0.w; }
  if(q1){ ps.x+=a1.x; ps.y+=a1.y; ps.z+=a1.z; ps.w+=a1.w;
          pq.x+=a1.x*a1.x; pq.y+=a1.y*a1.y; pq.z+=a1.z*a1.z; pq.w+=a1.w*a1.w; }
  if(q2){ ps.x+=a2.x; ps.y+=a2.y; ps.z+=a2.z; ps.w+=a2.w;
          pq.x+=a2.x*a2.x; pq.y+=a2.y*a2.y; pq.z+=a2.z*a2.z; pq.w+=a2.w*a2.w; }
  if(q3){ ps.x+=a3.x; ps.y+=a3.y; ps.z+=a3.z; ps.w+=a3.w;
          pq.x+=a3.x*a3.x; pq.y+=a3.y*a3.y; pq.z+=a3.z*a3.z; pq.w+=a3.w*a3.w; }
  __syncthreads();
  float* red = w1s;                   // reuse as 8 groups x 256
  int g = t >> 5;
  *(float4*)(red + g*256 +       jq*4) = ps;
  *(float4*)(red + g*256 + 128 + jq*4) = pq;
  __syncthreads();
  float a = 0.f;
  #pragma unroll
  for(int gg=0; gg<8; ++gg) a += red[gg*256 + t];
  part[(size_t)blockIdx.x*256 + t] = a;
}

// 32 blocks, no atomics: bnp[32][256]
__global__ __launch_bounds__(256) void k_bnred2(const float* __restrict__ part, float* __restrict__ bnp, int nblk){
  int t = threadIdx.x;
  float a = 0.f;
  for(int b = blockIdx.x; b < nblk; b += 32) a += part[(size_t)b*256 + t];
  bnp[blockIdx.x*256 + t] = a;
}

__global__ __launch_bounds__(128) void k_bnfold(const float* __restrict__ bnp, const float* __restrict__ g,
                                                const float* __restrict__ be, float* __restrict__ sb, float invN){
  int j = threadIdx.x;
  float s = 0.f, q = 0.f;
  for(int b=0;b<32;++b){ s += bnp[b*256 + j]; q += bnp[b*256 + 128 + j]; }
  float mu = s*invN;
  float var = q*invN - mu*mu;
  float sc = g[j] * rsqrtf(var + 1e-5f);
  sb[j] = sc;
  sb[128+j] = be[j] - mu*sc;
}

// ---------------- MLP part 2 (+bf16 shadow output for next gather) ----------------
__global__ __launch_bounds__(256) void k_mlp2(const float* __restrict__ h1, const float* __restrict__ sb,
                                              const float* __restrict__ w2, const float* __restrict__ b2,
                                              float* __restrict__ hout, ushort_t* __restrict__ h16, int N){
  __shared__ float act[64*132];
  int t = threadIdx.x;
  int n0 = blockIdx.x*64;
  // vectorized staging: 8 float4 per thread
  #pragma unroll
  for(int r=0; r<8; ++r){
    int idx = r*256 + t;          // float4 index; 32 float4 per row
    int nl = idx >> 5, k4 = idx & 31;
    int n = n0 + nl;
    float4 v = {0.f,0.f,0.f,0.f};
    if(n < N) v = ((const float4*)h1)[(size_t)n*32 + k4];
    float4 sc = ((const float4*)sb)[k4];
    float4 of = ((const float4*)sb)[32 + k4];
    v.x = fmaxf(v.x*sc.x + of.x, 0.f);
    v.y = fmaxf(v.y*sc.y + of.y, 0.f);
    v.z = fmaxf(v.z*sc.z + of.z, 0.f);
    v.w = fmaxf(v.w*sc.w + of.w, 0.f);
    *(float4*)(act + nl*132 + k4*4) = v;
  }
  __syncthreads();
  int cq = t & 15, m0 = (t >> 4)*4;
  const float4* w2v = (const float4*)w2;
  float4 acc0, acc1, acc2, acc3;
  acc0 = acc1 = acc2 = acc3 = *(const float4*)(b2 + cq*4);
  for(int k=0; k<128; ++k){
    float4 w = w2v[k*16 + cq];
    float a0 = act[(m0+0)*132 + k];
    float a1 = act[(m0+1)*132 + k];
    float a2 = act[(m0+2)*132 + k];
    float a3 = act[(m0+3)*132 + k];
    fma4(acc0, a0, w); fma4(acc1, a1, w); fma4(acc2, a2, w); fma4(acc3, a3, w);
  }
  acc0.x=fmaxf(acc0.x,0.f); acc0.y=fmaxf(acc0.y,0.f); acc0.z=fmaxf(acc0.z,0.f); acc0.w=fmaxf(acc0.w,0.f);
  acc1.x=fmaxf(acc1.x,0.f); acc1.y=fmaxf(acc1.y,0.f); acc1.z=fmaxf(acc1.z,0.f); acc1.w=fmaxf(acc1.w,0.f);
  acc2.x=fmaxf(acc2.x,0.f); acc2.y=fmaxf(acc2.y,0.f); acc2.z=fmaxf(acc2.z,0.f); acc2.w=fmaxf(acc2.w,0.f);
  acc3.x=fmaxf(acc3.x,0.f); acc3.y=fmaxf(acc3.y,0.f); acc3.z=fmaxf(acc3.z,0.f); acc3.w=fmaxf(acc3.w,0.f);
  if(n0+m0+0 < N){
    *(float4*)(hout + (size_t)(n0+m0+0)*64 + cq*4) = acc0;
    ushort4 b; b.x=f2bf(acc0.x); b.y=f2bf(acc0.y); b.z=f2bf(acc0.z); b.w=f2bf(acc0.w);
    *(ushort4*)(h16 + (size_t)(n0+m0+0)*64 + cq*4) = b;
  }
  if(n0+m0+1 < N){
    *(float4*)(hout + (size_t)(n0+m0+1)*64 + cq*4) = acc1;
    ushort4 b; b.x=f2bf(acc1.x); b.y=f2bf(acc1.y); b.z=f2bf(acc1.z); b.w=f2bf(acc1.w);
    *(ushort4*)(h16 + (size_t)(n0+m0+1)*64 + cq*4) = b;
  }
  if(n0+m0+2 < N){
    *(float4*)(hout + (size_t)(n0+m0+2)*64 + cq*4) = acc2;
    ushort4 b; b.x=f2bf(acc2.x); b.y=f2bf(acc2.y); b.z=f2bf(acc2.z); b.w=f2bf(acc2.w);
    *(ushort4*)(h16 + (size_t)(n0+m0+2)*64 + cq*4) = b;
  }
  if(n0+m0+3 < N){
    *(float4*)(hout + (size_t)(n0+m0+3)*64 + cq*4) = acc3;
    ushort4 b; b.x=f2bf(acc3.x); b.y=f2bf(acc3.y); b.z=f2bf(acc3.z); b.w=f2bf(acc3.w);
    *(ushort4*)(h16 + (size_t)(n0+m0+3)*64 + cq*4) = b;
  }
}

// ---------------- fused mean-pool + dense + sigmoid ----------------
__device__ __forceinline__ int lbound(const int* a, int n, int key){
  int lo = 0, hi = n;
  while(lo < hi){
    int mid = (lo + hi) >> 1;
    if(a[mid] < key) lo = mid + 1; else hi = mid;
  }
  return lo;
}

__global__ __launch_bounds__(256) void k_pool(const float* __restrict__ h, const int* __restrict__ batch,
                                              const float* __restrict__ wd, const float* __restrict__ bd,
                                              float* __restrict__ out, int N){
  int g = blockIdx.x;
  int lo = lbound(batch, N, g);
  int hi = lbound(batch, N, g+1);
  int c = threadIdx.x & 63, w = threadIdx.x >> 6;
  float acc = 0.f;
  for(int n = lo + w; n < hi; n += 4) acc += h[(size_t)n*64 + c];
  __shared__ float red[4][64];
  red[w][c] = acc;
  __syncthreads();
  if(w == 0){
    float v = red[0][c] + red[1][c] + red[2][c] + red[3][c];
    float count = (float)(hi - lo);
    v = v / fmaxf(count, 1.f) * wd[c];
    for(int off=32; off>0; off>>=1) v += __shfl_down(v, off, 64);
    if(c == 0) out[g] = 1.f / (1.f + expf(-(v + bd[0])));
  }
}

// ---------------- host ----------------

extern "C" void kernel_launch(void* const* d_in, const int* in_sizes, int n_in,
                              void* d_out, int out_size, void* d_ws, size_t ws_size,
                              hipStream_t stream){
  const float* x      = (const float*)d_in[0];
  const int*   ei     = (const int*)  d_in[1];
  const int*   batch  = (const int*)  d_in[2];
  const float* w_src  = (const float*)d_in[3];
  const float* b_src  = (const float*)d_in[4];
  const float* w_dst  = (const float*)d_in[5];
  const float* b_dst  = (const float*)d_in[6];
  const float* w_dense= (const float*)d_in[25];
  const float* b_dense= (const float*)d_in[26];
  float* out = (float*)d_out;

  const int N = in_sizes[2];
  const int E = in_sizes[1] / 2;
  const int* src = ei;
  const int* dst = ei + E;

  char* ws = (char*)d_ws;
  size_t off = 0;
  auto take = [&](size_t bytes) -> void* {
    void* p = ws + off;
    off += (bytes + 255) & ~(size_t)255;
    return p;
  };
  const int nblk1 = (N + 31) / 32;
  float*    hA   = (float*)   take((size_t)N*64*4);
  float*    hB   = (float*)   take((size_t)N*64*4);
  float*    hy   = (float*)   take((size_t)N*64*4);
  float*    h1   = (float*)   take((size_t)N*128*4);
  ushort_t* h16  = (ushort_t*)take((size_t)N*64*2);
  int*      esrc = (int*)     take((size_t)E*4);
  int*      cntn = (int*)     take((size_t)N*4);
  int*      rp   = (int*)     take((size_t)(N+1)*4);
  int*      cur  = (int*)     take((size_t)N*4);
  int*      bsum = (int*)     take(1024*4);
  float*    bnp  = (float*)   take(32*256*4);
  float*    sb   = (float*)   take(256*4);
  float*    part = (float*)   take((size_t)nblk1*256*4);

  const int nb256 = (N + 255) / 256;
  const int gN64  = (N*64 + 255) / 256;

  const unsigned w4 = (unsigned)((N + 3) / 4);
  const unsigned magic = (unsigned)(((1ull << 32) + w4 - 1) / w4);

  // ---- CSR by dst ----
  (void)hipMemsetAsync(cntn, 0, (size_t)N*4, stream);
  k_hist     <<<(E/4 + 255)/256, 256, 0, stream>>>(dst, cntn, E);
  k_scan_part<<<nb256, 256, 0, stream>>>(cntn, bsum, N);
  k_scan_top <<<1,     512, 0, stream>>>(bsum, rp, nb256, N);
  k_scan_down<<<nb256, 256, 0, stream>>>(cntn, bsum, rp, cur, N);
  {
    int nchunks = (E + 2047) / 2048;
    k_scatter<<<nchunks*4, 256, 0, stream>>>(src, dst, cur, esrc, E, magic);
  }

  // ---- layer-1 input projections ----
  k_proj<<<gN64, 256, 0, stream>>>(x, w_src, b_src, w_dst, b_dst, hA, hB, h16, N);

  // ---- 3 conv layers ----
  const float* xd_l[3]  = { hB, hA, hB };
  float*       out_l[3] = { hA, hB, hA };
  const float invN = 1.0f / (float)N;

  for(int L=0; L<3; ++L){
    const float* w1 = (const float*)d_in[7 + 6*L + 0];
    const float* b1 = (const float*)d_in[7 + 6*L + 1];
    const float* g  = (const float*)d_in[7 + 6*L + 2];
    const float* be = (const float*)d_in[7 + 6*L + 3];
    const float* w2 = (const float*)d_in[7 + 6*L + 4];
    const float* b2 = (const float*)d_in[7 + 6*L + 5];

    k_edge<<<gN64, 256, 0, stream>>>(h16, xd_l[L], rp, esrc, hy, N);
    k_mlp1<<<nblk1, 256, 0, stream>>>(hy, w1, b1, h1, part, N);
    k_bnred2<<<32, 256, 0, stream>>>(part, bnp, nblk1);
    k_bnfold<<<1,  128, 0, stream>>>(bnp, g, be, sb, invN);
    k_mlp2<<<(N+63)/64, 256, 0, stream>>>(h1, sb, w2, b2, out_l[L], h16, N);
  }

  // ---- pooled dense + sigmoid ----
  k_pool<<<512, 256, 0, stream>>>(out_l[2], batch, w_dense, b_dense, out, N);
}

// Round 8
// 710.514 us; speedup vs baseline: 2.0697x; 1.1320x over previous
//
#include <hip/hip_runtime.h>

typedef unsigned short ushort_t;
typedef __attribute__((ext_vector_type(8))) short bf16x8;
typedef __attribute__((ext_vector_type(4))) float f32x4;

__device__ __forceinline__ unsigned short f2bf(float f){
  unsigned u = __float_as_uint(f);
  u = (u + 0x7FFFu + ((u >> 16) & 1u)) >> 16;     // round-to-nearest-even
  return (unsigned short)u;
}
__device__ __forceinline__ float bf2f(unsigned short h){
  return __uint_as_float(((unsigned)h) << 16);
}

__device__ __forceinline__ void nt_load8(const int* __restrict__ p, int* out){
  #pragma unroll
  for(int k=0;k<8;++k) out[k] = __builtin_nontemporal_load(p + k);
}

// ---------------- CSR build ----------------

__global__ __launch_bounds__(256) void k_hist(const int* __restrict__ dst, int* __restrict__ cnt, int E){
  int base = (blockIdx.x*256 + threadIdx.x)*4;
  if(base + 4 <= E){
    int d0 = __builtin_nontemporal_load(dst + base + 0);
    int d1 = __builtin_nontemporal_load(dst + base + 1);
    int d2 = __builtin_nontemporal_load(dst + base + 2);
    int d3 = __builtin_nontemporal_load(dst + base + 3);
    atomicAdd(&cnt[d0], 1); atomicAdd(&cnt[d1], 1);
    atomicAdd(&cnt[d2], 1); atomicAdd(&cnt[d3], 1);
  } else {
    for(int i=base; i<E; ++i) atomicAdd(&cnt[dst[i]], 1);
  }
}

__global__ __launch_bounds__(256) void k_scan_part(const int* __restrict__ cnt, int* __restrict__ bsum, int N){
  __shared__ int s[256];
  int t = threadIdx.x;
  int i = blockIdx.x*256 + t;
  s[t] = (i < N) ? cnt[i] : 0;
  __syncthreads();
  for(int off=128; off>0; off>>=1){
    if(t < off) s[t] += s[t+off];
    __syncthreads();
  }
  if(t == 0) bsum[blockIdx.x] = s[0];
}

__global__ __launch_bounds__(512) void k_scan_top(int* __restrict__ bsum, int* __restrict__ rp, int nb, int N){
  __shared__ int s[512];
  int t = threadIdx.x;
  int v = (t < nb) ? bsum[t] : 0;
  s[t] = v;
  __syncthreads();
  for(int off=1; off<512; off<<=1){
    int x = 0;
    if(t >= off) x = s[t-off];
    __syncthreads();
    if(t >= off) s[t] += x;
    __syncthreads();
  }
  if(t < nb) bsum[t] = s[t] - v;
  if(t == 511) rp[N] = s[511];
}

__global__ __launch_bounds__(256) void k_scan_down(const int* __restrict__ cnt, const int* __restrict__ bsum,
                                                   int* __restrict__ rp, int* __restrict__ cur, int N){
  __shared__ int s[256];
  int t = threadIdx.x;
  int i = blockIdx.x*256 + t;
  int v = (i < N) ? cnt[i] : 0;
  s[t] = v;
  __syncthreads();
  for(int off=1; off<256; off<<=1){
    int x = 0;
    if(t >= off) x = s[t-off];
    __syncthreads();
    if(t >= off) s[t] += x;
    __syncthreads();
  }
  if(i < N){
    int p = bsum[blockIdx.x] + s[t] - v;
    rp[i] = p;
    cur[i] = p;
  }
}

// XCD-affine scatter: 4 dst-buckets; block class = blockIdx&3.
__global__ __launch_bounds__(256) void k_scatter(const int* __restrict__ src, const int* __restrict__ dst,
                                                 int* __restrict__ cur, int* __restrict__ esrc,
                                                 int E, unsigned magic){
  const int cls = blockIdx.x & 3;
  const int chunk = blockIdx.x >> 2;
  int base = chunk*2048 + threadIdx.x*8;
  if(base >= E) return;
  if(base + 8 <= E){
    int dd[8], ss[8];
    nt_load8(dst + base, dd);
    nt_load8(src + base, ss);
    #pragma unroll
    for(int k=0;k<8;++k){
      int d = dd[k];
      int b = (int)(((unsigned long long)(unsigned)d * magic) >> 32);
      b = b > 3 ? 3 : b;
      if(b == cls){
        int p = atomicAdd(&cur[d], 1);
        esrc[p] = ss[k];
      }
    }
  } else {
    for(int i=base; i<E; ++i){
      int d = dst[i];
      int b = (int)(((unsigned long long)(unsigned)d * magic) >> 32);
      b = b > 3 ? 3 : b;
      if(b == cls){
        int p = atomicAdd(&cur[d], 1);
        esrc[p] = src[i];
      }
    }
  }
}

// ---------------- layer 0 input projections ----------------
__global__ __launch_bounds__(256) void k_proj(const float* __restrict__ x,
                                              const float* __restrict__ ws, const float* __restrict__ bs,
                                              const float* __restrict__ wd, const float* __restrict__ bd,
                                              float* __restrict__ hs, float* __restrict__ hd,
                                              ushort_t* __restrict__ h16, int N){
  int gid = blockIdx.x*256 + threadIdx.x;
  int n = gid >> 6, c = gid & 63;
  if(n >= N) return;
  float as = bs[c], ad = bd[c];
  const float* xr = x + (size_t)n*9;
  #pragma unroll
  for(int k=0;k<9;++k){
    float xv = xr[k];
    as += xv * ws[k*64 + c];
    ad += xv * wd[k*64 + c];
  }
  hs[(size_t)n*64 + c] = as;
  hd[(size_t)n*64 + c] = ad;
  h16[(size_t)n*64 + c] = f2bf(as);
}

// ---------------- edge phase: direct-exp softmax aggregation, 8 streams ----------------
// msg in [1e-7, ~5] => exp cannot overflow; max-shift cancels algebraically.
// Output y is bf16 (feeds the MFMA mlp1).
__global__ __launch_bounds__(256) void k_edge(const ushort_t* __restrict__ xs16, const float* __restrict__ xd,
                                              const int* __restrict__ rp, const int* __restrict__ es,
                                              ushort_t* __restrict__ y16, int N){
  int gid = blockIdx.x*256 + threadIdx.x;
  int n = gid >> 6, lane = gid & 63;
  if(n >= N) return;
  int beg = rp[n], end = rp[n+1];

  float ss[8], tt[8];
  #pragma unroll
  for(int j=0;j<8;++j){ ss[j]=0.f; tt[j]=0.f; }

  int e = beg;
  for(; e + 8 <= end; e += 8){
    int idx[8];
    #pragma unroll
    for(int j=0;j<8;++j) idx[j] = es[e+j];
    float g[8];
    #pragma unroll
    for(int j=0;j<8;++j) g[j] = fmaxf(bf2f(xs16[(size_t)idx[j]*64 + lane]), 0.f) + 1e-7f;
    #pragma unroll
    for(int j=0;j<8;++j){
      float p = __expf(g[j]);
      ss[j] += p; tt[j] += p*g[j];
    }
  }
  for(; e < end; ++e){
    int i0 = es[e];
    float g = fmaxf(bf2f(xs16[(size_t)i0*64 + lane]), 0.f) + 1e-7f;
    float p = __expf(g);
    ss[0] += p; tt[0] += p*g;
  }
  float S = ((ss[0]+ss[1])+(ss[2]+ss[3])) + ((ss[4]+ss[5])+(ss[6]+ss[7]));
  float T = ((tt[0]+tt[1])+(tt[2]+tt[3])) + ((tt[4]+tt[5])+(tt[6]+tt[7]));
  float aggr = T / (S + 1e-16f);
  y16[(size_t)n*64 + lane] = f2bf(aggr + xd[(size_t)n*64 + lane]);
}

// ---------------- MLP part 1 (MFMA): h1 = y @ w1 + b1, bf16 in/out ----------------
// 32 nodes/block, 4 waves. Wave w: col-tiles {2w,2w+1} x node-tiles {0,1}, K=64 in 2 chunks.
// A[m=lane&15][k=quad*8+j] from global y16; C/D: col=lane&15, row=quad*4+reg.
// BN partials (sum,sumsq per col) from fp32 accumulators -> part (no h1 re-read).
__global__ __launch_bounds__(256) void k_mlp1(const ushort_t* __restrict__ y16, const float* __restrict__ w1,
                                              const float* __restrict__ b1, ushort_t* __restrict__ h1,
                                              float* __restrict__ part, int N){
  __shared__ float lds_s[128];
  __shared__ float lds_q[128];
  int t = threadIdx.x;
  int w = t >> 6, lane = t & 63;
  int ln = lane & 15, quad = lane >> 4;
  int nbase = blockIdx.x * 32;

  // B-frags: B[k][n] = w1[k*128+n], n = ct*16+ln, k = q*32+quad*8+j  (fp32 -> bf16)
  bf16x8 B[2][2];
  #pragma unroll
  for(int c=0;c<2;++c){
    int n = (2*w+c)*16 + ln;
    #pragma unroll
    for(int q=0;q<2;++q){
      bf16x8 f;
      #pragma unroll
      for(int j=0;j<8;++j){
        int k = q*32 + quad*8 + j;
        f[j] = (short)f2bf(w1[k*128 + n]);
      }
      B[c][q] = f;
    }
  }

  f32x4 z = {0.f,0.f,0.f,0.f};
  f32x4 acc[2][2] = {{z,z},{z,z}};
  #pragma unroll
  for(int q=0;q<2;++q){
    #pragma unroll
    for(int tt=0;tt<2;++tt){
      int m = nbase + tt*16 + ln;
      bf16x8 A;
      if(m < N) A = *(const bf16x8*)(y16 + (size_t)m*64 + q*32 + quad*8);
      else      A = (bf16x8)(short)0;
      #pragma unroll
      for(int c=0;c<2;++c)
        acc[tt][c] = __builtin_amdgcn_mfma_f32_16x16x32_bf16(A, B[c][q], acc[tt][c], 0,0,0);
    }
  }

  // epilogue: +bias, store bf16, BN partials
  float s[2] = {0.f, 0.f}, qq[2] = {0.f, 0.f};
  #pragma unroll
  for(int c=0;c<2;++c){
    int n = (2*w+c)*16 + ln;
    float bb = b1[n];
    #pragma unroll
    for(int tt=0;tt<2;++tt){
      int mrow = nbase + tt*16 + quad*4;
      #pragma unroll
      for(int r=0;r<4;++r){
        int m = mrow + r;
        if(m < N){
          float v = acc[tt][c][r] + bb;
          h1[(size_t)m*128 + n] = f2bf(v);
          s[c] += v; qq[c] += v*v;
        }
      }
    }
  }
  #pragma unroll
  for(int c=0;c<2;++c){
    float vs = s[c], vq = qq[c];
    vs += __shfl_down(vs, 32, 64); vs += __shfl_down(vs, 16, 64);
    vq += __shfl_down(vq, 32, 64); vq += __shfl_down(vq, 16, 64);
    if(quad == 0){
      lds_s[(2*w+c)*16 + ln] = vs;
      lds_q[(2*w+c)*16 + ln] = vq;
    }
  }
  __syncthreads();
  if(t < 128) part[(size_t)blockIdx.x*256 + t] = lds_s[t];
  else        part[(size_t)blockIdx.x*256 + t] = lds_q[t-128];
}

// 32 blocks, no atomics: bnp[32][256]
__global__ __launch_bounds__(256) void k_bnred2(const float* __restrict__ part, float* __restrict__ bnp, int nblk){
  int t = threadIdx.x;
  float a = 0.f;
  for(int b = blockIdx.x; b < nblk; b += 32) a += part[(size_t)b*256 + t];
  bnp[blockIdx.x*256 + t] = a;
}

__global__ __launch_bounds__(128) void k_bnfold(const float* __restrict__ bnp, const float* __restrict__ g,
                                                const float* __restrict__ be, float* __restrict__ sb, float invN){
  int j = threadIdx.x;
  float s = 0.f, q = 0.f;
  for(int b=0;b<32;++b){ s += bnp[b*256 + j]; q += bnp[b*256 + 128 + j]; }
  float mu = s*invN;
  float var = q*invN - mu*mu;
  float sc = g[j] * rsqrtf(var + 1e-5f);
  sb[j] = sc;
  sb[128+j] = be[j] - mu*sc;
}

// ---------------- MLP part 2 (MFMA): hout = relu(relu(bn(h1)) @ w2 + b2) ----------------
// 64 nodes/block, 4 waves. act = bn+relu(h1) staged to LDS bf16 (stride 136 shorts).
// Wave w: col-tile w (16 cols), node-tiles 0..3, K=128 in 4 chunks.
__global__ __launch_bounds__(256) void k_mlp2(const ushort_t* __restrict__ h1, const float* __restrict__ sb,
                                              const float* __restrict__ w2, const float* __restrict__ b2,
                                              float* __restrict__ hout, ushort_t* __restrict__ h16, int N){
  __shared__ ushort_t act[64*136];
  int t = threadIdx.x;
  int n0 = blockIdx.x*64;
  // staging: 64 rows x 128 cols bf16; 1024 chunks of 8 shorts
  #pragma unroll
  for(int r=0;r<4;++r){
    int idx = r*256 + t;
    int row = idx >> 4, k8 = (idx & 15)*8;
    int n = n0 + row;
    ushort_t tmp[8];
    if(n < N){
      *(uint4*)tmp = *(const uint4*)(h1 + (size_t)n*128 + k8);
    } else {
      #pragma unroll
      for(int j=0;j<8;++j) tmp[j] = 0;
    }
    #pragma unroll
    for(int j=0;j<8;++j){
      float v = bf2f(tmp[j]) * sb[k8+j] + sb[128+k8+j];
      tmp[j] = f2bf(fmaxf(v, 0.f));
    }
    *(uint4*)(act + row*136 + k8) = *(uint4*)tmp;
  }
  __syncthreads();
  int w = t >> 6, lane = t & 63;
  int ln = lane & 15, quad = lane >> 4;

  // B-frags: B[k][n] = w2[k*64+n], n = w*16+ln, k = q*32+quad*8+j
  bf16x8 B[4];
  #pragma unroll
  for(int q=0;q<4;++q){
    bf16x8 f;
    #pragma unroll
    for(int j=0;j<8;++j){
      int k = q*32 + quad*8 + j;
      f[j] = (short)f2bf(w2[k*64 + w*16 + ln]);
    }
    B[q] = f;
  }

  f32x4 z = {0.f,0.f,0.f,0.f};
  f32x4 acc[4] = {z,z,z,z};
  #pragma unroll
  for(int q=0;q<4;++q){
    #pragma unroll
    for(int tt=0;tt<4;++tt){
      bf16x8 A = *(const bf16x8*)(act + (tt*16 + ln)*136 + q*32 + quad*8);
      acc[tt] = __builtin_amdgcn_mfma_f32_16x16x32_bf16(A, B[q], acc[tt], 0,0,0);
    }
  }
  int n = w*16 + ln;
  float bb = b2[n];
  #pragma unroll
  for(int tt=0;tt<4;++tt){
    int mrow = n0 + tt*16 + quad*4;
    #pragma unroll
    for(int r=0;r<4;++r){
      int m = mrow + r;
      if(m < N){
        float v = fmaxf(acc[tt][r] + bb, 0.f);
        hout[(size_t)m*64 + n] = v;
        h16[(size_t)m*64 + n] = f2bf(v);
      }
    }
  }
}

// ---------------- fused mean-pool + dense + sigmoid ----------------
__device__ __forceinline__ int lbound(const int* a, int n, int key){
  int lo = 0, hi = n;
  while(lo < hi){
    int mid = (lo + hi) >> 1;
    if(a[mid] < key) lo = mid + 1; else hi = mid;
  }
  return lo;
}

__global__ __launch_bounds__(256) void k_pool(const float* __restrict__ h, const int* __restrict__ batch,
                                              const float* __restrict__ wd, const float* __restrict__ bd,
                                              float* __restrict__ out, int N){
  int g = blockIdx.x;
  int lo = lbound(batch, N, g);
  int hi = lbound(batch, N, g+1);
  int c = threadIdx.x & 63, w = threadIdx.x >> 6;
  float acc = 0.f;
  for(int n = lo + w; n < hi; n += 4) acc += h[(size_t)n*64 + c];
  __shared__ float red[4][64];
  red[w][c] = acc;
  __syncthreads();
  if(w == 0){
    float v = red[0][c] + red[1][c] + red[2][c] + red[3][c];
    float count = (float)(hi - lo);
    v = v / fmaxf(count, 1.f) * wd[c];
    for(int off=32; off>0; off>>=1) v += __shfl_down(v, off, 64);
    if(c == 0) out[g] = 1.f / (1.f + expf(-(v + bd[0])));
  }
}

// ---------------- host ----------------

extern "C" void kernel_launch(void* const* d_in, const int* in_sizes, int n_in,
                              void* d_out, int out_size, void* d_ws, size_t ws_size,
                              hipStream_t stream){
  const float* x      = (const float*)d_in[0];
  const int*   ei     = (const int*)  d_in[1];
  const int*   batch  = (const int*)  d_in[2];
  const float* w_src  = (const float*)d_in[3];
  const float* b_src  = (const float*)d_in[4];
  const float* w_dst  = (const float*)d_in[5];
  const float* b_dst  = (const float*)d_in[6];
  const float* w_dense= (const float*)d_in[25];
  const float* b_dense= (const float*)d_in[26];
  float* out = (float*)d_out;

  const int N = in_sizes[2];
  const int E = in_sizes[1] / 2;
  const int* src = ei;
  const int* dst = ei + E;

  char* ws = (char*)d_ws;
  size_t off = 0;
  auto take = [&](size_t bytes) -> void* {
    void* p = ws + off;
    off += (bytes + 255) & ~(size_t)255;
    return p;
  };
  const int nblk1 = (N + 31) / 32;
  float*    hA   = (float*)   take((size_t)N*64*4);
  float*    hB   = (float*)   take((size_t)N*64*4);
  ushort_t* hy16 = (ushort_t*)take((size_t)N*64*2);
  ushort_t* h1   = (ushort_t*)take((size_t)N*128*2);
  ushort_t* h16  = (ushort_t*)take((size_t)N*64*2);
  int*      esrc = (int*)     take((size_t)E*4);
  int*      cntn = (int*)     take((size_t)N*4);
  int*      rp   = (int*)     take((size_t)(N+1)*4);
  int*      cur  = (int*)     take((size_t)N*4);
  int*      bsum = (int*)     take(1024*4);
  float*    bnp  = (float*)   take(32*256*4);
  float*    sb   = (float*)   take(256*4);
  float*    part = (float*)   take((size_t)nblk1*256*4);

  const int nb256 = (N + 255) / 256;
  const int gN64  = (N*64 + 255) / 256;

  const unsigned w4 = (unsigned)((N + 3) / 4);
  const unsigned magic = (unsigned)(((1ull << 32) + w4 - 1) / w4);

  // ---- CSR by dst ----
  (void)hipMemsetAsync(cntn, 0, (size_t)N*4, stream);
  k_hist     <<<(E/4 + 255)/256, 256, 0, stream>>>(dst, cntn, E);
  k_scan_part<<<nb256, 256, 0, stream>>>(cntn, bsum, N);
  k_scan_top <<<1,     512, 0, stream>>>(bsum, rp, nb256, N);
  k_scan_down<<<nb256, 256, 0, stream>>>(cntn, bsum, rp, cur, N);
  {
    int nchunks = (E + 2047) / 2048;
    k_scatter<<<nchunks*4, 256, 0, stream>>>(src, dst, cur, esrc, E, magic);
  }

  // ---- layer-1 input projections ----
  k_proj<<<gN64, 256, 0, stream>>>(x, w_src, b_src, w_dst, b_dst, hA, hB, h16, N);

  // ---- 3 conv layers ----
  const float* xd_l[3]  = { hB, hA, hB };
  float*       out_l[3] = { hA, hB, hA };
  const float invN = 1.0f / (float)N;

  for(int L=0; L<3; ++L){
    const float* w1 = (const float*)d_in[7 + 6*L + 0];
    const float* b1 = (const float*)d_in[7 + 6*L + 1];
    const float* g  = (const float*)d_in[7 + 6*L + 2];
    const float* be = (const float*)d_in[7 + 6*L + 3];
    const float* w2 = (const float*)d_in[7 + 6*L + 4];
    const float* b2 = (const float*)d_in[7 + 6*L + 5];

    k_edge<<<gN64, 256, 0, stream>>>(h16, xd_l[L], rp, esrc, hy16, N);
    k_mlp1<<<nblk1, 256, 0, stream>>>(hy16, w1, b1, h1, part, N);
    k_bnred2<<<32, 256, 0, stream>>>(part, bnp, nblk1);
    k_bnfold<<<1,  128, 0, stream>>>(bnp, g, be, sb, invN);
    k_mlp2<<<(N+63)/64, 256, 0, stream>>>(h1, sb, w2, b2, out_l[L], h16, N);
  }

  // ---- pooled dense + sigmoid ----
  k_pool<<<512, 256, 0, stream>>>(out_l[2], batch, w_dense, b_dense, out, N);
}

// Round 9
// 653.884 us; speedup vs baseline: 2.2490x; 1.0866x over previous
//
#include <hip/hip_runtime.h>

typedef unsigned short ushort_t;
typedef __attribute__((ext_vector_type(8))) short bf16x8;
typedef __attribute__((ext_vector_type(4))) float f32x4;

__device__ __forceinline__ unsigned short f2bf(float f){
  unsigned u = __float_as_uint(f);
  u = (u + 0x7FFFu + ((u >> 16) & 1u)) >> 16;     // round-to-nearest-even
  return (unsigned short)u;
}
__device__ __forceinline__ float bf2f(unsigned short h){
  return __uint_as_float(((unsigned)h) << 16);
}

// ---------------- CSR build ----------------

__global__ __launch_bounds__(256) void k_hist(const int* __restrict__ dst, int* __restrict__ cnt, int E){
  int base = (blockIdx.x*256 + threadIdx.x)*4;
  if(base + 4 <= E){
    int d0 = __builtin_nontemporal_load(dst + base + 0);
    int d1 = __builtin_nontemporal_load(dst + base + 1);
    int d2 = __builtin_nontemporal_load(dst + base + 2);
    int d3 = __builtin_nontemporal_load(dst + base + 3);
    atomicAdd(&cnt[d0], 1); atomicAdd(&cnt[d1], 1);
    atomicAdd(&cnt[d2], 1); atomicAdd(&cnt[d3], 1);
  } else {
    for(int i=base; i<E; ++i) atomicAdd(&cnt[dst[i]], 1);
  }
}

__global__ __launch_bounds__(256) void k_scan_part(const int* __restrict__ cnt, int* __restrict__ bsum, int N){
  __shared__ int s[256];
  int t = threadIdx.x;
  int i = blockIdx.x*256 + t;
  s[t] = (i < N) ? cnt[i] : 0;
  __syncthreads();
  for(int off=128; off>0; off>>=1){
    if(t < off) s[t] += s[t+off];
    __syncthreads();
  }
  if(t == 0) bsum[blockIdx.x] = s[0];
}

__global__ __launch_bounds__(512) void k_scan_top(int* __restrict__ bsum, int* __restrict__ rp, int nb, int N){
  __shared__ int s[512];
  int t = threadIdx.x;
  int v = (t < nb) ? bsum[t] : 0;
  s[t] = v;
  __syncthreads();
  for(int off=1; off<512; off<<=1){
    int x = 0;
    if(t >= off) x = s[t-off];
    __syncthreads();
    if(t >= off) s[t] += x;
    __syncthreads();
  }
  if(t < nb) bsum[t] = s[t] - v;
  if(t == 511) rp[N] = s[511];
}

__global__ __launch_bounds__(256) void k_scan_down(const int* __restrict__ cnt, const int* __restrict__ bsum,
                                                   int* __restrict__ rp, int N){
  __shared__ int s[256];
  int t = threadIdx.x;
  int i = blockIdx.x*256 + t;
  int v = (i < N) ? cnt[i] : 0;
  s[t] = v;
  __syncthreads();
  for(int off=1; off<256; off<<=1){
    int x = 0;
    if(t >= off) x = s[t-off];
    __syncthreads();
    if(t >= off) s[t] += x;
    __syncthreads();
  }
  if(i < N) rp[i] = bsum[blockIdx.x] + s[t] - v;
}

// bucket cursors: bcur[b] = rp[b<<8]  (bucket = 256 consecutive nodes)
__global__ __launch_bounds__(512) void k_binit(const int* __restrict__ rp, int* __restrict__ bcur, int NB){
  int t = threadIdx.x;
  if(t < NB) bcur[t] = rp[t << 8];
}

// Phase A: partition edges into dst-buckets. Each block: LDS histogram over
// buckets, one global atomicAdd per (block,bucket) reserves a contiguous run
// inside the bucket region (regions are exactly [rp[b*256], rp[(b+1)*256)) ),
// then writes packed (dstlow<<17 | src) as contiguous runs -> writes merge.
__global__ __launch_bounds__(256) void k_part(const int* __restrict__ src, const int* __restrict__ dst,
                                              int* __restrict__ bcur, unsigned* __restrict__ ebuf,
                                              int E, int NB){
  __shared__ int lcnt[512];
  __shared__ int lbase[512];
  int t = threadIdx.x;
  int base = blockIdx.x * 4096;
  for(int b=t; b<NB; b+=256) lcnt[b] = 0;
  __syncthreads();

  int srcv[16], dstv[16];
  #pragma unroll
  for(int r=0;r<16;++r){
    int i = base + r*256 + t;
    if(i < E){
      srcv[r] = __builtin_nontemporal_load(src + i);
      dstv[r] = __builtin_nontemporal_load(dst + i);
    } else dstv[r] = -1;
  }
  #pragma unroll
  for(int r=0;r<16;++r)
    if(dstv[r] >= 0) atomicAdd(&lcnt[dstv[r] >> 8], 1);
  __syncthreads();
  for(int b=t; b<NB; b+=256){
    int c = lcnt[b];
    lbase[b] = c ? atomicAdd(&bcur[b], c) : 0;
    lcnt[b] = 0;
  }
  __syncthreads();
  #pragma unroll
  for(int r=0;r<16;++r){
    if(dstv[r] >= 0){
      int b = dstv[r] >> 8;
      int p = lbase[b] + atomicAdd(&lcnt[b], 1);
      ebuf[p] = (((unsigned)dstv[r] & 255u) << 17) | (unsigned)srcv[r];
    }
  }
}

// Phase B: one block per bucket; per-node cursors in LDS; scatter inside the
// bucket's private ~16KB esrc window (single block -> full L2 write merge).
__global__ __launch_bounds__(256) void k_place(const int* __restrict__ rp, const unsigned* __restrict__ ebuf,
                                               int* __restrict__ esrc, int N){
  __shared__ int lcur[256];
  int t = threadIdx.x;
  int b = blockIdx.x;
  int n0 = b << 8;
  int n1 = n0 + 256; if(n1 > N) n1 = N;
  if(n0 + t < n1) lcur[t] = rp[n0 + t];
  __syncthreads();
  int e0 = rp[n0], e1 = rp[n1];
  for(int i = e0 + t; i < e1; i += 256){
    unsigned v = ebuf[i];
    int dl = (int)(v >> 17);
    int s  = (int)(v & 0x1FFFFu);
    int p = atomicAdd(&lcur[dl], 1);
    esrc[p] = s;
  }
}

// ---------------- layer 0 input projections (bf16 outputs) ----------------
__global__ __launch_bounds__(256) void k_proj(const float* __restrict__ x,
                                              const float* __restrict__ ws, const float* __restrict__ bs,
                                              const float* __restrict__ wd, const float* __restrict__ bd,
                                              ushort_t* __restrict__ hs16, ushort_t* __restrict__ hd16, int N){
  int gid = blockIdx.x*256 + threadIdx.x;
  int n = gid >> 6, c = gid & 63;
  if(n >= N) return;
  float as = bs[c], ad = bd[c];
  const float* xr = x + (size_t)n*9;
  #pragma unroll
  for(int k=0;k<9;++k){
    float xv = xr[k];
    as += xv * ws[k*64 + c];
    ad += xv * wd[k*64 + c];
  }
  hs16[(size_t)n*64 + c] = f2bf(as);
  hd16[(size_t)n*64 + c] = f2bf(ad);
}

// ---------------- edge phase: direct-exp softmax aggregation, 8 streams ----------------
// msg in [1e-7, ~5] => exp cannot overflow; max-shift cancels algebraically.
// xd16 == xs16 for layers 2/3 (reference uses _genconv(h,h,...)).
__global__ __launch_bounds__(256) void k_edge(const ushort_t* __restrict__ xs16, const ushort_t* __restrict__ xd16,
                                              const int* __restrict__ rp, const int* __restrict__ es,
                                              ushort_t* __restrict__ y16, int N){
  int gid = blockIdx.x*256 + threadIdx.x;
  int n = gid >> 6, lane = gid & 63;
  if(n >= N) return;
  int beg = rp[n], end = rp[n+1];

  float ss[8], tt[8];
  #pragma unroll
  for(int j=0;j<8;++j){ ss[j]=0.f; tt[j]=0.f; }

  int e = beg;
  for(; e + 8 <= end; e += 8){
    int idx[8];
    #pragma unroll
    for(int j=0;j<8;++j) idx[j] = es[e+j];
    float g[8];
    #pragma unroll
    for(int j=0;j<8;++j) g[j] = fmaxf(bf2f(xs16[(size_t)idx[j]*64 + lane]), 0.f) + 1e-7f;
    #pragma unroll
    for(int j=0;j<8;++j){
      float p = __expf(g[j]);
      ss[j] += p; tt[j] += p*g[j];
    }
  }
  for(; e < end; ++e){
    int i0 = es[e];
    float g = fmaxf(bf2f(xs16[(size_t)i0*64 + lane]), 0.f) + 1e-7f;
    float p = __expf(g);
    ss[0] += p; tt[0] += p*g;
  }
  float S = ((ss[0]+ss[1])+(ss[2]+ss[3])) + ((ss[4]+ss[5])+(ss[6]+ss[7]));
  float T = ((tt[0]+tt[1])+(tt[2]+tt[3])) + ((tt[4]+tt[5])+(tt[6]+tt[7]));
  float aggr = T / (S + 1e-16f);
  y16[(size_t)n*64 + lane] = f2bf(aggr + bf2f(xd16[(size_t)n*64 + lane]));
}

// ---------------- MLP part 1 (MFMA): h1 = y @ w1 + b1, bf16 in/out ----------------
__global__ __launch_bounds__(256) void k_mlp1(const ushort_t* __restrict__ y16, const float* __restrict__ w1,
                                              const float* __restrict__ b1, ushort_t* __restrict__ h1,
                                              float* __restrict__ part, int N){
  __shared__ float lds_s[128];
  __shared__ float lds_q[128];
  int t = threadIdx.x;
  int w = t >> 6, lane = t & 63;
  int ln = lane & 15, quad = lane >> 4;
  int nbase = blockIdx.x * 32;

  bf16x8 B[2][2];
  #pragma unroll
  for(int c=0;c<2;++c){
    int n = (2*w+c)*16 + ln;
    #pragma unroll
    for(int q=0;q<2;++q){
      bf16x8 f;
      #pragma unroll
      for(int j=0;j<8;++j){
        int k = q*32 + quad*8 + j;
        f[j] = (short)f2bf(w1[k*128 + n]);
      }
      B[c][q] = f;
    }
  }

  f32x4 z = {0.f,0.f,0.f,0.f};
  f32x4 acc[2][2] = {{z,z},{z,z}};
  #pragma unroll
  for(int q=0;q<2;++q){
    #pragma unroll
    for(int tt=0;tt<2;++tt){
      int m = nbase + tt*16 + ln;
      bf16x8 A;
      if(m < N) A = *(const bf16x8*)(y16 + (size_t)m*64 + q*32 + quad*8);
      else      A = (bf16x8)(short)0;
      #pragma unroll
      for(int c=0;c<2;++c)
        acc[tt][c] = __builtin_amdgcn_mfma_f32_16x16x32_bf16(A, B[c][q], acc[tt][c], 0,0,0);
    }
  }

  float s[2] = {0.f, 0.f}, qq[2] = {0.f, 0.f};
  #pragma unroll
  for(int c=0;c<2;++c){
    int n = (2*w+c)*16 + ln;
    float bb = b1[n];
    #pragma unroll
    for(int tt=0;tt<2;++tt){
      int mrow = nbase + tt*16 + quad*4;
      #pragma unroll
      for(int r=0;r<4;++r){
        int m = mrow + r;
        if(m < N){
          float v = acc[tt][c][r] + bb;
          h1[(size_t)m*128 + n] = f2bf(v);
          s[c] += v; qq[c] += v*v;
        }
      }
    }
  }
  #pragma unroll
  for(int c=0;c<2;++c){
    float vs = s[c], vq = qq[c];
    vs += __shfl_down(vs, 32, 64); vs += __shfl_down(vs, 16, 64);
    vq += __shfl_down(vq, 32, 64); vq += __shfl_down(vq, 16, 64);
    if(quad == 0){
      lds_s[(2*w+c)*16 + ln] = vs;
      lds_q[(2*w+c)*16 + ln] = vq;
    }
  }
  __syncthreads();
  if(t < 128) part[(size_t)blockIdx.x*256 + t] = lds_s[t];
  else        part[(size_t)blockIdx.x*256 + t] = lds_q[t-128];
}

// 32 blocks, no atomics: bnp[32][256]
__global__ __launch_bounds__(256) void k_bnred2(const float* __restrict__ part, float* __restrict__ bnp, int nblk){
  int t = threadIdx.x;
  float a = 0.f;
  for(int b = blockIdx.x; b < nblk; b += 32) a += part[(size_t)b*256 + t];
  bnp[blockIdx.x*256 + t] = a;
}

__global__ __launch_bounds__(128) void k_bnfold(const float* __restrict__ bnp, const float* __restrict__ g,
                                                const float* __restrict__ be, float* __restrict__ sb, float invN){
  int j = threadIdx.x;
  float s = 0.f, q = 0.f;
  for(int b=0;b<32;++b){ s += bnp[b*256 + j]; q += bnp[b*256 + 128 + j]; }
  float mu = s*invN;
  float var = q*invN - mu*mu;
  float sc = g[j] * rsqrtf(var + 1e-5f);
  sb[j] = sc;
  sb[128+j] = be[j] - mu*sc;
}

// ---------------- MLP part 2 (MFMA): h16 = relu(relu(bn(h1)) @ w2 + b2), bf16 out only ----------------
__global__ __launch_bounds__(256) void k_mlp2(const ushort_t* __restrict__ h1, const float* __restrict__ sb,
                                              const float* __restrict__ w2, const float* __restrict__ b2,
                                              ushort_t* __restrict__ h16, int N){
  __shared__ ushort_t act[64*136];
  int t = threadIdx.x;
  int n0 = blockIdx.x*64;
  #pragma unroll
  for(int r=0;r<4;++r){
    int idx = r*256 + t;
    int row = idx >> 4, k8 = (idx & 15)*8;
    int n = n0 + row;
    ushort_t tmp[8];
    if(n < N){
      *(uint4*)tmp = *(const uint4*)(h1 + (size_t)n*128 + k8);
    } else {
      #pragma unroll
      for(int j=0;j<8;++j) tmp[j] = 0;
    }
    #pragma unroll
    for(int j=0;j<8;++j){
      float v = bf2f(tmp[j]) * sb[k8+j] + sb[128+k8+j];
      tmp[j] = f2bf(fmaxf(v, 0.f));
    }
    *(uint4*)(act + row*136 + k8) = *(uint4*)tmp;
  }
  __syncthreads();
  int w = t >> 6, lane = t & 63;
  int ln = lane & 15, quad = lane >> 4;

  bf16x8 B[4];
  #pragma unroll
  for(int q=0;q<4;++q){
    bf16x8 f;
    #pragma unroll
    for(int j=0;j<8;++j){
      int k = q*32 + quad*8 + j;
      f[j] = (short)f2bf(w2[k*64 + w*16 + ln]);
    }
    B[q] = f;
  }

  f32x4 z = {0.f,0.f,0.f,0.f};
  f32x4 acc[4] = {z,z,z,z};
  #pragma unroll
  for(int q=0;q<4;++q){
    #pragma unroll
    for(int tt=0;tt<4;++tt){
      bf16x8 A = *(const bf16x8*)(act + (tt*16 + ln)*136 + q*32 + quad*8);
      acc[tt] = __builtin_amdgcn_mfma_f32_16x16x32_bf16(A, B[q], acc[tt], 0,0,0);
    }
  }
  int n = w*16 + ln;
  float bb = b2[n];
  #pragma unroll
  for(int tt=0;tt<4;++tt){
    int mrow = n0 + tt*16 + quad*4;
    #pragma unroll
    for(int r=0;r<4;++r){
      int m = mrow + r;
      if(m < N){
        float v = fmaxf(acc[tt][r] + bb, 0.f);
        h16[(size_t)m*64 + n] = f2bf(v);
      }
    }
  }
}

// ---------------- fused mean-pool + dense + sigmoid (bf16 input) ----------------
__device__ __forceinline__ int lbound(const int* a, int n, int key){
  int lo = 0, hi = n;
  while(lo < hi){
    int mid = (lo + hi) >> 1;
    if(a[mid] < key) lo = mid + 1; else hi = mid;
  }
  return lo;
}

__global__ __launch_bounds__(256) void k_pool(const ushort_t* __restrict__ h16, const int* __restrict__ batch,
                                              const float* __restrict__ wd, const float* __restrict__ bd,
                                              float* __restrict__ out, int N){
  int g = blockIdx.x;
  int lo = lbound(batch, N, g);
  int hi = lbound(batch, N, g+1);
  int c = threadIdx.x & 63, w = threadIdx.x >> 6;
  float acc = 0.f;
  for(int n = lo + w; n < hi; n += 4) acc += bf2f(h16[(size_t)n*64 + c]);
  __shared__ float red[4][64];
  red[w][c] = acc;
  __syncthreads();
  if(w == 0){
    float v = red[0][c] + red[1][c] + red[2][c] + red[3][c];
    float count = (float)(hi - lo);
    v = v / fmaxf(count, 1.f) * wd[c];
    for(int off=32; off>0; off>>=1) v += __shfl_down(v, off, 64);
    if(c == 0) out[g] = 1.f / (1.f + expf(-(v + bd[0])));
  }
}

// ---------------- host ----------------

extern "C" void kernel_launch(void* const* d_in, const int* in_sizes, int n_in,
                              void* d_out, int out_size, void* d_ws, size_t ws_size,
                              hipStream_t stream){
  const float* x      = (const float*)d_in[0];
  const int*   ei     = (const int*)  d_in[1];
  const int*   batch  = (const int*)  d_in[2];
  const float* w_src  = (const float*)d_in[3];
  const float* b_src  = (const float*)d_in[4];
  const float* w_dst  = (const float*)d_in[5];
  const float* b_dst  = (const float*)d_in[6];
  const float* w_dense= (const float*)d_in[25];
  const float* b_dense= (const float*)d_in[26];
  float* out = (float*)d_out;

  const int N = in_sizes[2];
  const int E = in_sizes[1] / 2;
  const int* src = ei;
  const int* dst = ei + E;

  char* ws = (char*)d_ws;
  size_t off = 0;
  auto take = [&](size_t bytes) -> void* {
    void* p = ws + off;
    off += (bytes + 255) & ~(size_t)255;
    return p;
  };
  const int nblk1 = (N + 31) / 32;
  ushort_t* hs16 = (ushort_t*)take((size_t)N*64*2);
  ushort_t* hd16 = (ushort_t*)take((size_t)N*64*2);
  ushort_t* hy16 = (ushort_t*)take((size_t)N*64*2);
  ushort_t* h1   = (ushort_t*)take((size_t)N*128*2);
  ushort_t* h16  = (ushort_t*)take((size_t)N*64*2);
  unsigned* ebuf = (unsigned*)take((size_t)E*4);
  int*      esrc = (int*)     take((size_t)E*4);
  int*      cntn = (int*)     take((size_t)N*4);
  int*      rp   = (int*)     take((size_t)(N+1)*4);
  int*      bsum = (int*)     take(1024*4);
  int*      bcur = (int*)     take(512*4);
  float*    bnp  = (float*)   take(32*256*4);
  float*    sb   = (float*)   take(256*4);
  float*    part = (float*)   take((size_t)nblk1*256*4);

  const int nb256 = (N + 255) / 256;
  const int gN64  = (N*64 + 255) / 256;
  const int NB    = (N + 255) >> 8;             // buckets of 256 nodes

  // ---- CSR by dst (2-phase bucket partition) ----
  (void)hipMemsetAsync(cntn, 0, (size_t)N*4, stream);
  k_hist     <<<(E/4 + 255)/256, 256, 0, stream>>>(dst, cntn, E);
  k_scan_part<<<nb256, 256, 0, stream>>>(cntn, bsum, N);
  k_scan_top <<<1,     512, 0, stream>>>(bsum, rp, nb256, N);
  k_scan_down<<<nb256, 256, 0, stream>>>(cntn, bsum, rp, N);
  k_binit    <<<1,     512, 0, stream>>>(rp, bcur, NB);
  k_part     <<<(E + 4095)/4096, 256, 0, stream>>>(src, dst, bcur, ebuf, E, NB);
  k_place    <<<NB,    256, 0, stream>>>(rp, ebuf, esrc, N);

  // ---- layer-1 input projections ----
  k_proj<<<gN64, 256, 0, stream>>>(x, w_src, b_src, w_dst, b_dst, hs16, hd16, N);

  // ---- 3 conv layers (layers 2/3: xs == xd == h16, per reference _genconv(h,h)) ----
  const ushort_t* xs_l[3] = { hs16, h16, h16 };
  const ushort_t* xd_l[3] = { hd16, h16, h16 };
  const float invN = 1.0f / (float)N;

  for(int L=0; L<3; ++L){
    const float* w1 = (const float*)d_in[7 + 6*L + 0];
    const float* b1 = (const float*)d_in[7 + 6*L + 1];
    const float* g  = (const float*)d_in[7 + 6*L + 2];
    const float* be = (const float*)d_in[7 + 6*L + 3];
    const float* w2 = (const float*)d_in[7 + 6*L + 4];
    const float* b2 = (const float*)d_in[7 + 6*L + 5];

    k_edge<<<gN64, 256, 0, stream>>>(xs_l[L], xd_l[L], rp, esrc, hy16, N);
    k_mlp1<<<nblk1, 256, 0, stream>>>(hy16, w1, b1, h1, part, N);
    k_bnred2<<<32, 256, 0, stream>>>(part, bnp, nblk1);
    k_bnfold<<<1,  128, 0, stream>>>(bnp, g, be, sb, invN);
    k_mlp2<<<(N+63)/64, 256, 0, stream>>>(h1, sb, w2, b2, h16, N);
  }

  // ---- pooled dense + sigmoid ----
  k_pool<<<512, 256, 0, stream>>>(h16, batch, w_dense, b_dense, out, N);
}